// Round 1
// baseline (624.039 us; speedup 1.0000x reference)
//
#include <hip/hip_runtime.h>

// DeltaNet chunkwise delta rule. b=2,h=8,L=4096,d=128,chunk=32.
// R5: scan critical path de-latencied.
//  - all __shfl_xor(.,32) (ds_bpermute, ~100cy lgkm stalls) -> v_permlane32_swap
//    (VALU). One swap yields BOTH needed fragment words.
//  - f32->bf16 pack via v_cvt_pk_bf16_f32 (1 inst per pair vs ~8 VALU).
//  - U-accum: 4 independent 2-deep MFMA chains + add tree (was 2x4-deep).
//  - O-accum split into two 5-deep chains, summed at store.
//  - S-updates issued before final O MFMAs (they gate the next chunk).
//  - 4 col-group waves of one head merged into one 256-thread block for
//    same-CU L1 sharing of the (colBase-independent) wA/kA/atA/qa streams.

#define Bb 2
#define Hh 8
#define Ll 4096
#define Dd 128
#define DP (Dd + 4)
#define Cc 32
#define CP (Cc + 4)
#define NC (Ll / Cc)       // 128 chunks
#define BHn (Bb * Hh)      // 16 heads

typedef float  f32x16 __attribute__((ext_vector_type(16)));
typedef short  bf16x8 __attribute__((ext_vector_type(8)));

__device__ __forceinline__ short f2bf(float x) {
    union { float f; unsigned u; } a; a.f = x;
    const unsigned r = a.u + 0x7FFFu + ((a.u >> 16) & 1u);  // RNE
    return (short)(r >> 16);
}

__device__ __forceinline__ unsigned cvt_pk_bf16(float lo, float hi) {
    unsigned r;
    asm("v_cvt_pk_bf16_f32 %0, %1, %2" : "=v"(r) : "v"(lo), "v"(hi));
    return r;
}

// C-layout quadrant (row = (reg&3)+8*(reg>>2)+4*half, col = lane&31) ->
// MFMA B-operand fragment for K=16 slice m.
// permlane32_swap(a,b): r[0] = lanes<32: a(own)   | lanes>=32: b(lane-32)
//                       r[1] = lanes<32: a(lane+32)| lanes>=32: b(own)
// word j   needs (A_j own | Bv_j from lower)  -> r[0] of swap(a_pair, b_pair)
// word j+4 needs (A_j from upper | Bv_j own)  -> r[1]
__device__ __forceinline__ bf16x8 mk_bop(const f32x16& T, int m) {
    const int o = 8 * m;
    const unsigned a01 = cvt_pk_bf16(T[o + 0], T[o + 1]);
    const unsigned a23 = cvt_pk_bf16(T[o + 2], T[o + 3]);
    const unsigned b01 = cvt_pk_bf16(T[o + 4], T[o + 5]);
    const unsigned b23 = cvt_pk_bf16(T[o + 6], T[o + 7]);
    const auto r0 = __builtin_amdgcn_permlane32_swap(a01, b01, false, false);
    const auto r1 = __builtin_amdgcn_permlane32_swap(a23, b23, false, false);
    union { unsigned u[4]; bf16x8 v; } out;
    out.u[0] = r0[0]; out.u[1] = r1[0]; out.u[2] = r0[1]; out.u[3] = r1[1];
    return out.v;
}

// ---------------------------------------------------------------------------
// Kernel 1: per-(head,chunk) precompute. 2048 blocks x 256. (unchanged)
// ---------------------------------------------------------------------------
template <bool QNB>
__global__ __launch_bounds__(256) void prep_kernel(
    const float* __restrict__ q, const float* __restrict__ k,
    const float* __restrict__ v, const float* __restrict__ beta,
    float* __restrict__ wsU, float* __restrict__ wsNq,
    short* __restrict__ wsWb, short* __restrict__ wsKtb,
    short* __restrict__ wsAttnb, short* __restrict__ wsQnb)
{
    __shared__ float sK[Cc][DP];
    __shared__ float sQ[Cc][DP];
    __shared__ float sV[Cc][DP];
    __shared__ float sA[Cc][CP];
    __shared__ float sInv[Cc][CP];
    __shared__ float sBeta[Cc], sNk[Cc], sNq[Cc];

    const int tid = threadIdx.x;
    const int blk = blockIdx.x;          // bh*NC + ch
    const int bh = blk / NC;
    const int ch = blk % NC;
    const size_t base = (size_t)(bh * Ll + ch * Cc) * Dd;

    for (int e = tid; e < Cc * Dd / 4; e += 256) {
        const int r = e >> 5, c4 = e & 31;
        ((float4*)&sQ[r][0])[c4] = ((const float4*)(q + base))[e];
        ((float4*)&sK[r][0])[c4] = ((const float4*)(k + base))[e];
        ((float4*)&sV[r][0])[c4] = ((const float4*)(v + base))[e];
    }
    if (tid < Cc) sBeta[tid] = beta[bh * Ll + ch * Cc + tid];
    __syncthreads();

    // row norms: 4 lanes per row, rows 0..31 = k, 32..63 = q
    {
        const int row = tid >> 2, part = tid & 3;
        const float* src = (row < Cc) ? &sK[row][0] : &sQ[row - Cc][0];
        float s = 0.f;
        #pragma unroll
        for (int j = 0; j < 8; ++j) {
            const float4 t = ((const float4*)src)[part + j * 4];
            s += t.x * t.x + t.y * t.y + t.z * t.z + t.w * t.w;
        }
        s += __shfl_xor(s, 1);
        s += __shfl_xor(s, 2);
        if (part == 0) {
            const float r = 1.0f / sqrtf(s);
            if (row < Cc) sNk[row] = r; else sNq[row - Cc] = r;
        }
    }
    __syncthreads();

    if (tid < Cc) wsNq[bh * Ll + ch * Cc + tid] = sNq[tid];

    for (int e = tid; e < Cc * Dd / 4; e += 256) {
        const int r = e >> 5, c4 = e & 31;
        float4 kk = ((float4*)&sK[r][0])[c4];
        float4 qq = ((float4*)&sQ[r][0])[c4];
        float4 vv = ((float4*)&sV[r][0])[c4];
        const float nk = sNk[r], nq = sNq[r], bb = sBeta[r];
        kk.x *= nk; kk.y *= nk; kk.z *= nk; kk.w *= nk;
        qq.x *= nq; qq.y *= nq; qq.z *= nq; qq.w *= nq;
        vv.x *= bb; vv.y *= bb; vv.z *= bb; vv.w *= bb;
        ((float4*)&sK[r][0])[c4] = kk;
        ((float4*)&sQ[r][0])[c4] = qq;
        ((float4*)&sV[r][0])[c4] = vv;
    }
    __syncthreads();

    // A[i][j] = beta_i * dot(kn_i, kn_j); sInv = I
    for (int e = tid; e < Cc * Cc; e += 256) {
        const int i = e >> 5, j = e & 31;
        const float4* ri = (const float4*)&sK[i][0];
        const float4* rj = (const float4*)&sK[j][0];
        float s = 0.f;
        for (int x = 0; x < Dd / 4; ++x) {
            const float4 a = ri[x], b = rj[x];
            s += a.x * b.x + a.y * b.y + a.z * b.z + a.w * b.w;
        }
        sA[i][j] = s * sBeta[i];
        sInv[i][j] = (i == j) ? 1.0f : 0.0f;
    }
    __syncthreads();

    // forward substitution (unit lower triangular inverse)
    for (int i = 1; i < Cc; ++i) {
        if (tid < i) {
            const int j = tid;
            float s = 0.f;
            for (int m = j; m < i; ++m) s += sA[i][m] * sInv[m][j];
            sInv[i][j] = -s;
        }
        __syncthreads();
    }

    // u = inv @ (v*beta) fp32 ; wsWb = -(inv @ (kn*beta)) bf16
    const size_t cbase = (size_t)blk * Cc * Dd;
    for (int e = tid; e < Cc * Dd; e += 256) {
        const int c = e >> 7, dd = e & 127;
        float su = 0.f, sw = 0.f;
        for (int f = 0; f <= c; ++f) {
            const float iv = sInv[c][f];
            su += iv * sV[f][dd];
            sw += iv * sBeta[f] * sK[f][dd];
        }
        wsU[cbase + e] = su;
        wsWb[cbase + e] = f2bf(-sw);
    }

    // wsKtb[dd][c] = kn[c][dd]
    for (int e = tid; e < Cc * Dd; e += 256) {
        const int dd = e >> 5, cc = e & 31;
        wsKtb[cbase + e] = f2bf(sK[cc][dd]);
    }

    // qn bf16 (fast path only)
    if (QNB) {
        for (int e = tid; e < Cc * Dd; e += 256) {
            const int c = e >> 7, dd = e & 127;
            wsQnb[cbase + e] = f2bf(sQ[c][dd]);
        }
    }

    // attn = tril(qn @ kn^T)  (bf16)
    const size_t abase = (size_t)blk * Cc * Cc;
    for (int e = tid; e < Cc * Cc; e += 256) {
        const int i = e >> 5, j = e & 31;
        float s = 0.f;
        if (j <= i) {
            const float4* ri = (const float4*)&sQ[i][0];
            const float4* rj = (const float4*)&sK[j][0];
            for (int x = 0; x < Dd / 4; ++x) {
                const float4 a = ri[x], b = rj[x];
                s += a.x * b.x + a.y * b.y + a.z * b.z + a.w * b.w;
            }
        }
        wsAttnb[abase + e] = f2bf(s);
    }
}

// ---------------------------------------------------------------------------
// Kernel 2: MFMA scan, register double-buffered, permlane half-exchange.
// Grid (16 heads) x 256 threads (4 col-group waves sharing one CU's L1).
// ---------------------------------------------------------------------------
struct Ops {
    bf16x8 wA[8], kA[8], atA[2];
    f32x16 U;
    bf16x8 qa[8];     // QNB path
    float4 qr[16];    // raw-q path
    float  rq;        // raw-q path
};

template <bool QNB>
__device__ __forceinline__ void load_ops(
    Ops& B, int bh, int ch, int colBase, int c, int h,
    const float* __restrict__ q, const short* __restrict__ wsQnb,
    const short* __restrict__ wsWb, const short* __restrict__ wsKtb,
    const short* __restrict__ wsAttnb, const float* __restrict__ wsU,
    const float* __restrict__ wsNq)
{
    const size_t cb = (size_t)(bh * NC + ch) * (Cc * Dd);
    const size_t ab = (size_t)(bh * NC + ch) * (Cc * Cc);
    #pragma unroll
    for (int ks = 0; ks < 8; ++ks)
        B.wA[ks] = ((const bf16x8*)(wsWb + cb))[c * 16 + 2 * ks + h];
    if constexpr (QNB) {
        #pragma unroll
        for (int ks = 0; ks < 8; ++ks)
            B.qa[ks] = ((const bf16x8*)(wsQnb + cb))[c * 16 + 2 * ks + h];
    } else {
        const size_t qb = (size_t)(bh * Ll + ch * Cc) * Dd;
        B.rq = wsNq[bh * Ll + ch * Cc + c];
        #pragma unroll
        for (int ks = 0; ks < 8; ++ks) {
            B.qr[2 * ks]     = ((const float4*)(q + qb))[c * 32 + 4 * ks + 2 * h];
            B.qr[2 * ks + 1] = ((const float4*)(q + qb))[c * 32 + 4 * ks + 2 * h + 1];
        }
    }
    #pragma unroll
    for (int t = 0; t < 4; ++t)
        #pragma unroll
        for (int m = 0; m < 2; ++m)
            B.kA[t * 2 + m] =
                ((const bf16x8*)(wsKtb + cb))[(32 * t + c) * 4 + 2 * m + h];
    B.atA[0] = ((const bf16x8*)(wsAttnb + ab))[c * 4 + h];
    B.atA[1] = ((const bf16x8*)(wsAttnb + ab))[c * 4 + 2 + h];
    #pragma unroll
    for (int r = 0; r < 16; ++r) {
        const int row = (r & 3) + 8 * (r >> 2) + 4 * h;
        B.U[r] = wsU[cb + (size_t)row * Dd + colBase + c];
    }
}

template <bool QNB>
__device__ __forceinline__ void compute_chunk(
    const Ops& B, int bh, int ch, int colBase, int c, int h,
    f32x16& S0, f32x16& S1, f32x16& S2, f32x16& S3, float* __restrict__ out)
{
    bf16x8 qaL[8];
    if constexpr (!QNB) {
        const float rq = B.rq;
        #pragma unroll
        for (int ks = 0; ks < 8; ++ks) {
            const float4 a = B.qr[2 * ks], b = B.qr[2 * ks + 1];
            union { unsigned u[4]; bf16x8 v; } t;
            t.u[0] = cvt_pk_bf16(a.x * rq, a.y * rq);
            t.u[1] = cvt_pk_bf16(a.z * rq, a.w * rq);
            t.u[2] = cvt_pk_bf16(b.x * rq, b.y * rq);
            t.u[3] = cvt_pk_bf16(b.z * rq, b.w * rq);
            qaL[ks] = t.v;
        }
    }

    // 4 independent U chains (2-deep each) + 2 independent O chains (5-deep)
    f32x16 Ua = B.U, Ub, Uc, Ud, O1, O2;
    #pragma unroll
    for (int r = 0; r < 16; ++r) { Ub[r]=0.f; Uc[r]=0.f; Ud[r]=0.f; O1[r]=0.f; O2[r]=0.f; }

    #pragma unroll
    for (int ks = 0; ks < 8; ++ks) {
        const f32x16& T = (ks < 2) ? S0 : (ks < 4) ? S1 : (ks < 6) ? S2 : S3;
        const bf16x8 sB = mk_bop(T, ks & 1);
        f32x16& Ux = (ks < 2) ? Ua : (ks < 4) ? Ub : (ks < 6) ? Uc : Ud;
        Ux = __builtin_amdgcn_mfma_f32_32x32x16_bf16(B.wA[ks], sB, Ux, 0, 0, 0);
        if constexpr (QNB) {
            if (ks & 1)
                O2 = __builtin_amdgcn_mfma_f32_32x32x16_bf16(B.qa[ks], sB, O2, 0, 0, 0);
            else
                O1 = __builtin_amdgcn_mfma_f32_32x32x16_bf16(B.qa[ks], sB, O1, 0, 0, 0);
        } else {
            if (ks & 1)
                O2 = __builtin_amdgcn_mfma_f32_32x32x16_bf16(qaL[ks], sB, O2, 0, 0, 0);
            else
                O1 = __builtin_amdgcn_mfma_f32_32x32x16_bf16(qaL[ks], sB, O1, 0, 0, 0);
        }
    }

    f32x16 Us;
    #pragma unroll
    for (int r = 0; r < 16; ++r) Us[r] = (Ua[r] + Ub[r]) + (Uc[r] + Ud[r]);

    const bf16x8 uB0 = mk_bop(Us, 0);
    const bf16x8 uB1 = mk_bop(Us, 1);

    // S updates first — they gate the next chunk's sB builds.
    S0 = __builtin_amdgcn_mfma_f32_32x32x16_bf16(B.kA[0], uB0, S0, 0, 0, 0);
    S0 = __builtin_amdgcn_mfma_f32_32x32x16_bf16(B.kA[1], uB1, S0, 0, 0, 0);
    S1 = __builtin_amdgcn_mfma_f32_32x32x16_bf16(B.kA[2], uB0, S1, 0, 0, 0);
    S1 = __builtin_amdgcn_mfma_f32_32x32x16_bf16(B.kA[3], uB1, S1, 0, 0, 0);
    S2 = __builtin_amdgcn_mfma_f32_32x32x16_bf16(B.kA[4], uB0, S2, 0, 0, 0);
    S2 = __builtin_amdgcn_mfma_f32_32x32x16_bf16(B.kA[5], uB1, S2, 0, 0, 0);
    S3 = __builtin_amdgcn_mfma_f32_32x32x16_bf16(B.kA[6], uB0, S3, 0, 0, 0);
    S3 = __builtin_amdgcn_mfma_f32_32x32x16_bf16(B.kA[7], uB1, S3, 0, 0, 0);

    O1 = __builtin_amdgcn_mfma_f32_32x32x16_bf16(B.atA[0], uB0, O1, 0, 0, 0);
    O2 = __builtin_amdgcn_mfma_f32_32x32x16_bf16(B.atA[1], uB1, O2, 0, 0, 0);

    const size_t qb = (size_t)(bh * Ll + ch * Cc) * Dd;
    #pragma unroll
    for (int r = 0; r < 16; ++r) {
        const int row = (r & 3) + 8 * (r >> 2) + 4 * h;
        out[qb + (size_t)row * Dd + colBase + c] = O1[r] + O2[r];
    }
}

template <bool QNB>
__global__ __launch_bounds__(256, 1) void scan_kernel(
    const float* __restrict__ q, const float* __restrict__ wsU,
    const short* __restrict__ wsWb, const short* __restrict__ wsKtb,
    const short* __restrict__ wsAttnb, const short* __restrict__ wsQnb,
    const float* __restrict__ wsNq, float* __restrict__ out)
{
    const int lane = threadIdx.x & 63;
    const int h = lane >> 5;
    const int c = lane & 31;
    const int bh = blockIdx.x;
    const int colBase = (threadIdx.x >> 6) << 5;   // wave id * 32

    f32x16 S0, S1, S2, S3;
    #pragma unroll
    for (int r = 0; r < 16; ++r) { S0[r]=0.f; S1[r]=0.f; S2[r]=0.f; S3[r]=0.f; }

    Ops A, B;
    load_ops<QNB>(A, bh, 0, colBase, c, h, q, wsQnb, wsWb, wsKtb, wsAttnb,
                  wsU, wsNq);
    for (int ch = 0; ch < NC; ch += 2) {
        load_ops<QNB>(B, bh, ch + 1, colBase, c, h, q, wsQnb, wsWb, wsKtb,
                      wsAttnb, wsU, wsNq);
        compute_chunk<QNB>(A, bh, ch, colBase, c, h, S0, S1, S2, S3, out);
        load_ops<QNB>(A, bh, (ch + 2 < NC) ? ch + 2 : ch, colBase, c, h, q,
                      wsQnb, wsWb, wsKtb, wsAttnb, wsU, wsNq);
        compute_chunk<QNB>(B, bh, ch + 1, colBase, c, h, S0, S1, S2, S3, out);
    }

    // S_final -> d_out tail
    const size_t soff = (size_t)Bb * Hh * Ll * Dd;
    #pragma unroll
    for (int t = 0; t < 4; ++t) {
        const f32x16& T = (t == 0) ? S0 : (t == 1) ? S1 : (t == 2) ? S2 : S3;
        #pragma unroll
        for (int r = 0; r < 16; ++r) {
            const int row = 32 * t + (r & 3) + 8 * (r >> 2) + 4 * h;
            out[soff + (size_t)bh * Dd * Dd + (size_t)row * Dd + colBase + c] =
                T[r];
        }
    }
}

extern "C" void kernel_launch(void* const* d_in, const int* in_sizes, int n_in,
                              void* d_out, int out_size, void* d_ws,
                              size_t ws_size, hipStream_t stream) {
    const float* q    = (const float*)d_in[0];
    const float* k    = (const float*)d_in[1];
    const float* v    = (const float*)d_in[2];
    const float* beta = (const float*)d_in[3];
    float* out = (float*)d_out;

    const size_t nQK = (size_t)BHn * Ll * Dd;          // 8,388,608
    float* wsU    = (float*)d_ws;                      // fp32, 32 MB
    float* wsNq   = wsU + nQK;                         // fp32, 0.25 MB
    short* wsWb   = (short*)(wsNq + (size_t)BHn * Ll); // bf16, 16 MB
    short* wsKtb  = wsWb + nQK;                        // bf16, 16 MB
    short* wsAttnb = wsKtb + nQK;                      // bf16, 4 MB
    short* wsQnb  = wsAttnb + (size_t)BHn * NC * Cc * Cc; // bf16, 16 MB (opt)
    const size_t need_qnb = (size_t)((char*)(wsQnb + nQK) - (char*)d_ws);

    if (ws_size >= need_qnb) {
        prep_kernel<true><<<dim3(BHn * NC), 256, 0, stream>>>(
            q, k, v, beta, wsU, wsNq, wsWb, wsKtb, wsAttnb, wsQnb);
        scan_kernel<true><<<dim3(BHn), 256, 0, stream>>>(
            q, wsU, wsWb, wsKtb, wsAttnb, wsQnb, wsNq, out);
    } else {
        prep_kernel<false><<<dim3(BHn * NC), 256, 0, stream>>>(
            q, k, v, beta, wsU, wsNq, wsWb, wsKtb, wsAttnb, wsQnb);
        scan_kernel<false><<<dim3(BHn), 256, 0, stream>>>(
            q, wsU, wsWb, wsKtb, wsAttnb, wsQnb, wsNq, out);
    }
}

// Round 2
// 475.991 us; speedup vs baseline: 1.3110x; 1.3110x over previous
//
#include <hip/hip_runtime.h>

// DeltaNet chunkwise delta rule. b=2,h=8,L=4096,d=128,chunk=32.
// R6: scan prefetch moved from registers (impossible: 2xOps=240 VGPR) to LDS
// via global_load_lds async DMA, counted vmcnt(30) pipeline (T3/T4).
//  - grid back to 64 blocks x 64 thr (R5's 16x256 concentrated the operand
//    stream on 16 CUs -> 1.5x regression; 64 CUs spreads it).
//  - ws layouts rewritten fragment-major by prep so every scan LDS read is a
//    lane-contiguous ds_read_b128 (conflict-free), U row-major b32 (2-way=free).
//  - keep permlane32_swap + v_cvt_pk_bf16_f32 half-exchange (proven correct).

#define Bb 2
#define Hh 8
#define Ll 4096
#define Dd 128
#define DP (Dd + 4)
#define Cc 32
#define CP (Cc + 4)
#define NC (Ll / Cc)       // 128 chunks
#define BHn (Bb * Hh)      // 16 heads

// LDS slab layout (bytes, per buffer):
//   0     : Wb  frag-major [16 frag][32 c] bf16x8   = 8192
//   8192  : Ktb frag-major [16 frag][32 c] bf16x8   = 8192
//   16384 : Qnb frag-major [16 frag][32 c] bf16x8   = 8192 (QNB only)
//   24576 : At  frag-major [4 frag][32 c]  bf16x8   = 2048
//   26624 : U slice [32 row][32 col] f32            = 4096
#define SLAB 30720

typedef float  f32x16 __attribute__((ext_vector_type(16)));
typedef short  bf16x8 __attribute__((ext_vector_type(8)));

#define WAITVM(N) asm volatile("s_waitcnt vmcnt(" #N ")" ::: "memory")

__device__ __forceinline__ short f2bf(float x) {
    union { float f; unsigned u; } a; a.f = x;
    const unsigned r = a.u + 0x7FFFu + ((a.u >> 16) & 1u);  // RNE
    return (short)(r >> 16);
}

__device__ __forceinline__ unsigned cvt_pk_bf16(float lo, float hi) {
    unsigned r;
    asm("v_cvt_pk_bf16_f32 %0, %1, %2" : "=v"(r) : "v"(lo), "v"(hi));
    return r;
}

// C-layout quadrant -> MFMA B-operand fragment for K=16 slice m, via
// v_cvt_pk_bf16_f32 + v_permlane32_swap (VALU only, no LDS). Proven in R5.
__device__ __forceinline__ bf16x8 mk_bop(const f32x16& T, int m) {
    const int o = 8 * m;
    const unsigned a01 = cvt_pk_bf16(T[o + 0], T[o + 1]);
    const unsigned a23 = cvt_pk_bf16(T[o + 2], T[o + 3]);
    const unsigned b01 = cvt_pk_bf16(T[o + 4], T[o + 5]);
    const unsigned b23 = cvt_pk_bf16(T[o + 6], T[o + 7]);
    const auto r0 = __builtin_amdgcn_permlane32_swap(a01, b01, false, false);
    const auto r1 = __builtin_amdgcn_permlane32_swap(a23, b23, false, false);
    union { unsigned u[4]; bf16x8 v; } out;
    out.u[0] = r0[0]; out.u[1] = r1[0]; out.u[2] = r0[1]; out.u[3] = r1[1];
    return out.v;
}

__device__ __forceinline__ void gl_lds16(const void* gsrc, void* ldst) {
    __builtin_amdgcn_global_load_lds(
        (const __attribute__((address_space(1))) unsigned int*)gsrc,
        (__attribute__((address_space(3))) unsigned int*)ldst, 16, 0, 0);
}

// ---------------------------------------------------------------------------
// Kernel 1: per-(head,chunk) precompute. 2048 blocks x 256.
// Same math as before; Wb/Ktb/At/Qnb now written FRAGMENT-MAJOR.
// ---------------------------------------------------------------------------
template <bool QNB>
__global__ __launch_bounds__(256) void prep_kernel(
    const float* __restrict__ q, const float* __restrict__ k,
    const float* __restrict__ v, const float* __restrict__ beta,
    float* __restrict__ wsU, float* __restrict__ wsNq,
    short* __restrict__ wsWb, short* __restrict__ wsKtb,
    short* __restrict__ wsAttnb, short* __restrict__ wsQnb)
{
    __shared__ float sK[Cc][DP];
    __shared__ float sQ[Cc][DP];
    __shared__ float sV[Cc][DP];
    __shared__ float sA[Cc][CP];
    __shared__ float sInv[Cc][CP];
    __shared__ float sBeta[Cc], sNk[Cc], sNq[Cc];

    const int tid = threadIdx.x;
    const int blk = blockIdx.x;          // bh*NC + ch
    const int bh = blk / NC;
    const int ch = blk % NC;
    const size_t base = (size_t)(bh * Ll + ch * Cc) * Dd;

    for (int e = tid; e < Cc * Dd / 4; e += 256) {
        const int r = e >> 5, c4 = e & 31;
        ((float4*)&sQ[r][0])[c4] = ((const float4*)(q + base))[e];
        ((float4*)&sK[r][0])[c4] = ((const float4*)(k + base))[e];
        ((float4*)&sV[r][0])[c4] = ((const float4*)(v + base))[e];
    }
    if (tid < Cc) sBeta[tid] = beta[bh * Ll + ch * Cc + tid];
    __syncthreads();

    // row norms: 4 lanes per row, rows 0..31 = k, 32..63 = q
    {
        const int row = tid >> 2, part = tid & 3;
        const float* src = (row < Cc) ? &sK[row][0] : &sQ[row - Cc][0];
        float s = 0.f;
        #pragma unroll
        for (int j = 0; j < 8; ++j) {
            const float4 t = ((const float4*)src)[part + j * 4];
            s += t.x * t.x + t.y * t.y + t.z * t.z + t.w * t.w;
        }
        s += __shfl_xor(s, 1);
        s += __shfl_xor(s, 2);
        if (part == 0) {
            const float r = 1.0f / sqrtf(s);
            if (row < Cc) sNk[row] = r; else sNq[row - Cc] = r;
        }
    }
    __syncthreads();

    if (tid < Cc) wsNq[bh * Ll + ch * Cc + tid] = sNq[tid];

    for (int e = tid; e < Cc * Dd / 4; e += 256) {
        const int r = e >> 5, c4 = e & 31;
        float4 kk = ((float4*)&sK[r][0])[c4];
        float4 qq = ((float4*)&sQ[r][0])[c4];
        float4 vv = ((float4*)&sV[r][0])[c4];
        const float nk = sNk[r], nq = sNq[r], bb = sBeta[r];
        kk.x *= nk; kk.y *= nk; kk.z *= nk; kk.w *= nk;
        qq.x *= nq; qq.y *= nq; qq.z *= nq; qq.w *= nq;
        vv.x *= bb; vv.y *= bb; vv.z *= bb; vv.w *= bb;
        ((float4*)&sK[r][0])[c4] = kk;
        ((float4*)&sQ[r][0])[c4] = qq;
        ((float4*)&sV[r][0])[c4] = vv;
    }
    __syncthreads();

    // A[i][j] = beta_i * dot(kn_i, kn_j); sInv = I
    for (int e = tid; e < Cc * Cc; e += 256) {
        const int i = e >> 5, j = e & 31;
        const float4* ri = (const float4*)&sK[i][0];
        const float4* rj = (const float4*)&sK[j][0];
        float s = 0.f;
        for (int x = 0; x < Dd / 4; ++x) {
            const float4 a = ri[x], b = rj[x];
            s += a.x * b.x + a.y * b.y + a.z * b.z + a.w * b.w;
        }
        sA[i][j] = s * sBeta[i];
        sInv[i][j] = (i == j) ? 1.0f : 0.0f;
    }
    __syncthreads();

    // forward substitution (unit lower triangular inverse)
    for (int i = 1; i < Cc; ++i) {
        if (tid < i) {
            const int j = tid;
            float s = 0.f;
            for (int m = j; m < i; ++m) s += sA[i][m] * sInv[m][j];
            sInv[i][j] = -s;
        }
        __syncthreads();
    }

    // u = inv @ (v*beta) fp32 (row-major [c][dd]);
    // wsWb = -(inv @ (kn*beta)) bf16 FRAGMENT-MAJOR: idx = (dd>>3)*256 + c*8 + (dd&7)
    const size_t cbase = (size_t)blk * Cc * Dd;
    for (int e = tid; e < Cc * Dd; e += 256) {
        const int c = e >> 7, dd = e & 127;
        float su = 0.f, sw = 0.f;
        for (int f = 0; f <= c; ++f) {
            const float iv = sInv[c][f];
            su += iv * sV[f][dd];
            sw += iv * sBeta[f] * sK[f][dd];
        }
        wsU[cbase + e] = su;
        wsWb[cbase + ((dd >> 3) << 8) + (c << 3) + (dd & 7)] = f2bf(-sw);
    }

    // Ktb frag-major: value kn[cc][dd] at ((dd>>5)*4 + (cc>>3))*256 + (dd&31)*8 + (cc&7)
    for (int e = tid; e < Cc * Dd; e += 256) {
        const int dd = e >> 5, cc = e & 31;
        wsKtb[cbase + ((((dd >> 5) << 2) + (cc >> 3)) << 8) + ((dd & 31) << 3) +
              (cc & 7)] = f2bf(sK[cc][dd]);
    }

    // qn bf16 frag-major (fast path only)
    if (QNB) {
        for (int e = tid; e < Cc * Dd; e += 256) {
            const int c = e >> 7, dd = e & 127;
            wsQnb[cbase + ((dd >> 3) << 8) + (c << 3) + (dd & 7)] = f2bf(sQ[c][dd]);
        }
    }

    // attn = tril(qn @ kn^T) bf16 frag-major: attn[i][j] at (j>>3)*256 + i*8 + (j&7)
    const size_t abase = (size_t)blk * Cc * Cc;
    for (int e = tid; e < Cc * Cc; e += 256) {
        const int i = e >> 5, j = e & 31;
        float s = 0.f;
        if (j <= i) {
            const float4* ri = (const float4*)&sQ[i][0];
            const float4* rj = (const float4*)&sK[j][0];
            for (int x = 0; x < Dd / 4; ++x) {
                const float4 a = ri[x], b = rj[x];
                s += a.x * b.x + a.y * b.y + a.z * b.z + a.w * b.w;
            }
        }
        wsAttnb[abase + ((j >> 3) << 8) + (i << 3) + (j & 7)] = f2bf(s);
    }
}

// ---------------------------------------------------------------------------
// Kernel 2: MFMA scan. 64 blocks x 64 threads (1 wave/CU).
// LDS double-buffer staged by global_load_lds, counted vmcnt pipeline.
// ---------------------------------------------------------------------------
template <bool QNB>
__device__ __forceinline__ void stage(
    char* lbuf, int bh, int ch, int colBase, int lane,
    const short* __restrict__ wsWb, const short* __restrict__ wsKtb,
    const short* __restrict__ wsAttnb, const short* __restrict__ wsQnb,
    const float* __restrict__ wsU)
{
    const size_t cb = (size_t)(bh * NC + ch) * (Cc * Dd);
    const size_t ab = (size_t)(bh * NC + ch) * (Cc * Cc);
    const char* srcW = (const char*)(wsWb + cb);
    const char* srcK = (const char*)(wsKtb + cb);
    const char* srcA = (const char*)(wsAttnb + ab);
    const int l16 = lane * 16;
    #pragma unroll
    for (int g = 0; g < 8; ++g)
        gl_lds16(srcW + g * 1024 + l16, lbuf + g * 1024);
    #pragma unroll
    for (int g = 0; g < 8; ++g)
        gl_lds16(srcK + g * 1024 + l16, lbuf + 8192 + g * 1024);
    if constexpr (QNB) {
        const char* srcQ = (const char*)(wsQnb + cb);
        #pragma unroll
        for (int g = 0; g < 8; ++g)
            gl_lds16(srcQ + g * 1024 + l16, lbuf + 16384 + g * 1024);
    }
    #pragma unroll
    for (int g = 0; g < 2; ++g)
        gl_lds16(srcA + g * 1024 + l16, lbuf + 24576 + g * 1024);
    // U slice: LDS [row][32 col] f32; dest linear d = g*1024 + lane*16
    //   -> row = g*8 + lane/8, col4 = (lane&7)*4
    #pragma unroll
    for (int g = 0; g < 4; ++g) {
        const int row = g * 8 + (lane >> 3);
        const float* srcU = wsU + cb + (size_t)row * Dd + colBase + (lane & 7) * 4;
        gl_lds16(srcU, lbuf + 26624 + g * 1024);
    }
}
// loads per stage: QNB ? 30 : 22

template <bool QNB>
__device__ __forceinline__ void compute_chunk(
    const char* lbuf, int bh, int ch, int colBase, int c, int h,
    const float* __restrict__ q, const float* __restrict__ wsNq,
    f32x16& S0, f32x16& S1, f32x16& S2, f32x16& S3, float* __restrict__ out)
{
    const bf16x8* Wf = (const bf16x8*)(lbuf);
    const bf16x8* Kf = (const bf16x8*)(lbuf + 8192);
    const bf16x8* Qf = (const bf16x8*)(lbuf + 16384);
    const bf16x8* Af = (const bf16x8*)(lbuf + 24576);
    const float*  Uf = (const float*)(lbuf + 26624);

    bf16x8 qa[8];
    if constexpr (QNB) {
        #pragma unroll
        for (int ks = 0; ks < 8; ++ks) qa[ks] = Qf[(2 * ks + h) * 32 + c];
    } else {
        const size_t qb = (size_t)(bh * Ll + ch * Cc) * Dd;
        const float rq = wsNq[bh * Ll + ch * Cc + c];
        #pragma unroll
        for (int ks = 0; ks < 8; ++ks) {
            const float4 a = ((const float4*)(q + qb))[c * 32 + 4 * ks + 2 * h];
            const float4 b = ((const float4*)(q + qb))[c * 32 + 4 * ks + 2 * h + 1];
            union { unsigned u[4]; bf16x8 v; } t;
            t.u[0] = cvt_pk_bf16(a.x * rq, a.y * rq);
            t.u[1] = cvt_pk_bf16(a.z * rq, a.w * rq);
            t.u[2] = cvt_pk_bf16(b.x * rq, b.y * rq);
            t.u[3] = cvt_pk_bf16(b.z * rq, b.w * rq);
            qa[ks] = t.v;
        }
    }

    f32x16 Ua, Ub, O1, O2;
    #pragma unroll
    for (int r = 0; r < 16; ++r) {
        const int row = (r & 3) + 8 * (r >> 2) + 4 * h;
        Ua[r] = Uf[row * 32 + c];
        Ub[r] = 0.f; O1[r] = 0.f; O2[r] = 0.f;
    }

    #pragma unroll
    for (int ks = 0; ks < 8; ++ks) {
        const f32x16& T = (ks < 2) ? S0 : (ks < 4) ? S1 : (ks < 6) ? S2 : S3;
        const bf16x8 sB = mk_bop(T, ks & 1);
        const bf16x8 wA = Wf[(2 * ks + h) * 32 + c];
        if (ks < 4)
            Ua = __builtin_amdgcn_mfma_f32_32x32x16_bf16(wA, sB, Ua, 0, 0, 0);
        else
            Ub = __builtin_amdgcn_mfma_f32_32x32x16_bf16(wA, sB, Ub, 0, 0, 0);
        if (ks & 1)
            O2 = __builtin_amdgcn_mfma_f32_32x32x16_bf16(qa[ks], sB, O2, 0, 0, 0);
        else
            O1 = __builtin_amdgcn_mfma_f32_32x32x16_bf16(qa[ks], sB, O1, 0, 0, 0);
    }

    f32x16 Us;
    #pragma unroll
    for (int r = 0; r < 16; ++r) Us[r] = Ua[r] + Ub[r];

    const bf16x8 uB0 = mk_bop(Us, 0);
    const bf16x8 uB1 = mk_bop(Us, 1);

    // S updates first — they gate the next chunk's sB builds.
    S0 = __builtin_amdgcn_mfma_f32_32x32x16_bf16(Kf[(0 + h) * 32 + c],  uB0, S0, 0, 0, 0);
    S0 = __builtin_amdgcn_mfma_f32_32x32x16_bf16(Kf[(2 + h) * 32 + c],  uB1, S0, 0, 0, 0);
    S1 = __builtin_amdgcn_mfma_f32_32x32x16_bf16(Kf[(4 + h) * 32 + c],  uB0, S1, 0, 0, 0);
    S1 = __builtin_amdgcn_mfma_f32_32x32x16_bf16(Kf[(6 + h) * 32 + c],  uB1, S1, 0, 0, 0);
    S2 = __builtin_amdgcn_mfma_f32_32x32x16_bf16(Kf[(8 + h) * 32 + c],  uB0, S2, 0, 0, 0);
    S2 = __builtin_amdgcn_mfma_f32_32x32x16_bf16(Kf[(10 + h) * 32 + c], uB1, S2, 0, 0, 0);
    S3 = __builtin_amdgcn_mfma_f32_32x32x16_bf16(Kf[(12 + h) * 32 + c], uB0, S3, 0, 0, 0);
    S3 = __builtin_amdgcn_mfma_f32_32x32x16_bf16(Kf[(14 + h) * 32 + c], uB1, S3, 0, 0, 0);

    O1 = __builtin_amdgcn_mfma_f32_32x32x16_bf16(Af[(0 + h) * 32 + c], uB0, O1, 0, 0, 0);
    O2 = __builtin_amdgcn_mfma_f32_32x32x16_bf16(Af[(2 + h) * 32 + c], uB1, O2, 0, 0, 0);

    const size_t qb = (size_t)(bh * Ll + ch * Cc) * Dd;
    #pragma unroll
    for (int r = 0; r < 16; ++r) {
        const int row = (r & 3) + 8 * (r >> 2) + 4 * h;
        out[qb + (size_t)row * Dd + colBase + c] = O1[r] + O2[r];
    }
}

template <bool QNB>
__global__ __launch_bounds__(64, 1) void scan_kernel(
    const float* __restrict__ q, const float* __restrict__ wsU,
    const short* __restrict__ wsWb, const short* __restrict__ wsKtb,
    const short* __restrict__ wsAttnb, const short* __restrict__ wsQnb,
    const float* __restrict__ wsNq, float* __restrict__ out)
{
    __shared__ __attribute__((aligned(16))) char lds[2][SLAB];

    const int lane = threadIdx.x;
    const int h = lane >> 5;
    const int c = lane & 31;
    const int bh = blockIdx.x;
    const int colBase = blockIdx.y * 32;

    f32x16 S0, S1, S2, S3;
    #pragma unroll
    for (int r = 0; r < 16; ++r) { S0[r]=0.f; S1[r]=0.f; S2[r]=0.f; S3[r]=0.f; }

    stage<QNB>(lds[0], bh, 0, colBase, lane, wsWb, wsKtb, wsAttnb, wsQnb, wsU);
    for (int ch = 0; ch < NC; ++ch) {
        if (ch + 1 < NC) {
            stage<QNB>(lds[(ch + 1) & 1], bh, ch + 1, colBase, lane,
                       wsWb, wsKtb, wsAttnb, wsQnb, wsU);
            if constexpr (QNB) WAITVM(30); else WAITVM(22);
        } else {
            WAITVM(0);
        }
        compute_chunk<QNB>(lds[ch & 1], bh, ch, colBase, c, h, q, wsNq,
                           S0, S1, S2, S3, out);
    }

    // S_final -> d_out tail
    const size_t soff = (size_t)Bb * Hh * Ll * Dd;
    #pragma unroll
    for (int t = 0; t < 4; ++t) {
        const f32x16& T = (t == 0) ? S0 : (t == 1) ? S1 : (t == 2) ? S2 : S3;
        #pragma unroll
        for (int r = 0; r < 16; ++r) {
            const int row = 32 * t + (r & 3) + 8 * (r >> 2) + 4 * h;
            out[soff + (size_t)bh * Dd * Dd + (size_t)row * Dd + colBase + c] =
                T[r];
        }
    }
}

extern "C" void kernel_launch(void* const* d_in, const int* in_sizes, int n_in,
                              void* d_out, int out_size, void* d_ws,
                              size_t ws_size, hipStream_t stream) {
    const float* q    = (const float*)d_in[0];
    const float* k    = (const float*)d_in[1];
    const float* v    = (const float*)d_in[2];
    const float* beta = (const float*)d_in[3];
    float* out = (float*)d_out;

    const size_t nQK = (size_t)BHn * Ll * Dd;          // 8,388,608
    float* wsU    = (float*)d_ws;                      // fp32, 32 MB
    float* wsNq   = wsU + nQK;                         // fp32, 0.25 MB
    short* wsWb   = (short*)(wsNq + (size_t)BHn * Ll); // bf16, 16 MB
    short* wsKtb  = wsWb + nQK;                        // bf16, 16 MB
    short* wsAttnb = wsKtb + nQK;                      // bf16, 4 MB
    short* wsQnb  = wsAttnb + (size_t)BHn * NC * Cc * Cc; // bf16, 16 MB (opt)
    const size_t need_qnb = (size_t)((char*)(wsQnb + nQK) - (char*)d_ws);

    if (ws_size >= need_qnb) {
        prep_kernel<true><<<dim3(BHn * NC), 256, 0, stream>>>(
            q, k, v, beta, wsU, wsNq, wsWb, wsKtb, wsAttnb, wsQnb);
        scan_kernel<true><<<dim3(BHn, 4), 64, 0, stream>>>(
            q, wsU, wsWb, wsKtb, wsAttnb, wsQnb, wsNq, out);
    } else {
        prep_kernel<false><<<dim3(BHn * NC), 256, 0, stream>>>(
            q, k, v, beta, wsU, wsNq, wsWb, wsKtb, wsAttnb, wsQnb);
        scan_kernel<false><<<dim3(BHn, 4), 64, 0, stream>>>(
            q, wsU, wsWb, wsKtb, wsAttnb, wsQnb, wsNq, out);
    }
}

// Round 3
// 353.324 us; speedup vs baseline: 1.7662x; 1.3472x over previous
//
#include <hip/hip_runtime.h>

// DeltaNet chunkwise delta rule. b=2,h=8,L=4096,d=128,chunk=32.
// R7: prep rebuilt (scan unchanged from R6).
//  - sQ/sV dropped from LDS (60.4->26 KB; occupancy 2->4+ blocks/CU).
//  - A and attn via 32x32x16 bf16 MFMA with 3-term hi/lo split (~fp32 acc).
//  - triangular inverse: per-column in-register recurrence on wave 0, zero
//    barriers (column j is self-contained; A rows broadcast-read from LDS).
//  - wave specialization: w0=A+inv, w1=attn, w2-3=Ktb/Qnb (short8 stores).
//  - u/w: register-blocked outer product over f; one ivb=inv*beta scalar
//    drives both v (global/L1) and k^ (LDS b128) rows; 5 barriers total.

#define Bb 2
#define Hh 8
#define Ll 4096
#define Dd 128
#define DP (Dd + 4)
#define Cc 32
#define CP2 33
#define NC (Ll / Cc)       // 128 chunks
#define BHn (Bb * Hh)      // 16 heads

// LDS slab layout for scan (bytes, per buffer):
//   0     : Wb  frag-major [16 frag][32 c] bf16x8   = 8192
//   8192  : Ktb frag-major [16 frag][32 c] bf16x8   = 8192
//   16384 : Qnb frag-major [16 frag][32 c] bf16x8   = 8192 (QNB only)
//   24576 : At  frag-major [4 frag][32 c]  bf16x8   = 2048
//   26624 : U slice [32 row][32 col] f32            = 4096
#define SLAB 30720

typedef float  f32x16 __attribute__((ext_vector_type(16)));
typedef short  bf16x8 __attribute__((ext_vector_type(8)));

#define WAITVM(N) asm volatile("s_waitcnt vmcnt(" #N ")" ::: "memory")

__device__ __forceinline__ short f2bf(float x) {
    union { float f; unsigned u; } a; a.f = x;
    const unsigned r = a.u + 0x7FFFu + ((a.u >> 16) & 1u);  // RNE
    return (short)(r >> 16);
}

__device__ __forceinline__ float bf2f(short h) {
    union { unsigned u; float f; } t;
    t.u = ((unsigned)(unsigned short)h) << 16;
    return t.f;
}

__device__ __forceinline__ unsigned cvt_pk_bf16(float lo, float hi) {
    unsigned r;
    asm("v_cvt_pk_bf16_f32 %0, %1, %2" : "=v"(r) : "v"(lo), "v"(hi));
    return r;
}

// C-layout quadrant -> MFMA B-operand fragment for K=16 slice m, via
// v_cvt_pk_bf16_f32 + v_permlane32_swap (VALU only, no LDS). Proven in R5/R6.
__device__ __forceinline__ bf16x8 mk_bop(const f32x16& T, int m) {
    const int o = 8 * m;
    const unsigned a01 = cvt_pk_bf16(T[o + 0], T[o + 1]);
    const unsigned a23 = cvt_pk_bf16(T[o + 2], T[o + 3]);
    const unsigned b01 = cvt_pk_bf16(T[o + 4], T[o + 5]);
    const unsigned b23 = cvt_pk_bf16(T[o + 6], T[o + 7]);
    const auto r0 = __builtin_amdgcn_permlane32_swap(a01, b01, false, false);
    const auto r1 = __builtin_amdgcn_permlane32_swap(a23, b23, false, false);
    union { unsigned u[4]; bf16x8 v; } out;
    out.u[0] = r0[0]; out.u[1] = r1[0]; out.u[2] = r0[1]; out.u[3] = r1[1];
    return out.v;
}

__device__ __forceinline__ void gl_lds16(const void* gsrc, void* ldst) {
    __builtin_amdgcn_global_load_lds(
        (const __attribute__((address_space(1))) unsigned int*)gsrc,
        (__attribute__((address_space(3))) unsigned int*)ldst, 16, 0, 0);
}

// split 8 fp32 into bf16 hi + bf16 residual lo (3-term split-MFMA inputs)
__device__ __forceinline__ void split8(const float4& a, const float4& b,
                                       bf16x8& hi, bf16x8& lo) {
    const float x[8] = {a.x, a.y, a.z, a.w, b.x, b.y, b.z, b.w};
    #pragma unroll
    for (int j = 0; j < 8; ++j) {
        const short hs = f2bf(x[j]);
        hi[j] = hs;
        lo[j] = f2bf(x[j] - bf2f(hs));
    }
}

__device__ __forceinline__ void fma4(float4& acc, float s, const float4& x) {
    acc.x += s * x.x; acc.y += s * x.y; acc.z += s * x.z; acc.w += s * x.w;
}

// ---------------------------------------------------------------------------
// Kernel 1: per-(head,chunk) precompute. 2048 blocks x 256.
// ---------------------------------------------------------------------------
template <bool QNB>
__global__ __launch_bounds__(256, 4) void prep_kernel(
    const float* __restrict__ q, const float* __restrict__ k,
    const float* __restrict__ v, const float* __restrict__ beta,
    float* __restrict__ wsU, float* __restrict__ wsNq,
    short* __restrict__ wsWb, short* __restrict__ wsKtb,
    short* __restrict__ wsAttnb, short* __restrict__ wsQnb)
{
    __shared__ float sK[Cc][DP];          // 16.9 KB (normalized k)
    __shared__ float sA[Cc][CP2];         // 4.2 KB
    __shared__ float sInv[Cc][CP2];       // 4.2 KB
    __shared__ float sBeta[Cc], sNk[Cc], sNq[Cc];

    const int tid = threadIdx.x;
    const int blk = blockIdx.x;          // bh*NC + ch
    const int bh = blk / NC;
    const int ch = blk % NC;
    const size_t base = (size_t)(bh * Ll + ch * Cc) * Dd;

    // ---- load k -> LDS; beta ----
    for (int e = tid; e < Cc * Dd / 4; e += 256) {
        const int r = e >> 5, c4 = e & 31;
        ((float4*)&sK[r][0])[c4] = ((const float4*)(k + base))[e];
    }
    if (tid < Cc) sBeta[tid] = beta[bh * Ll + ch * Cc + tid];
    __syncthreads();

    // ---- row norms: rows 0..31 = k (LDS), 32..63 = q (global) ----
    {
        const int row = tid >> 2, part = tid & 3;
        float s = 0.f;
        if (row < Cc) {
            const float4* src = (const float4*)&sK[row][0];
            #pragma unroll
            for (int j = 0; j < 8; ++j) {
                const float4 t = src[part + j * 4];
                s += t.x * t.x + t.y * t.y + t.z * t.z + t.w * t.w;
            }
        } else {
            const float4* src =
                (const float4*)(q + base + (size_t)(row - Cc) * Dd);
            #pragma unroll
            for (int j = 0; j < 8; ++j) {
                const float4 t = src[part + j * 4];
                s += t.x * t.x + t.y * t.y + t.z * t.z + t.w * t.w;
            }
        }
        s += __shfl_xor(s, 1);
        s += __shfl_xor(s, 2);
        if (part == 0) {
            const float r = 1.0f / sqrtf(s);
            if (row < Cc) sNk[row] = r; else sNq[row - Cc] = r;
        }
    }
    __syncthreads();

    if (tid < Cc) wsNq[bh * Ll + ch * Cc + tid] = sNq[tid];

    // ---- scale k rows in place ----
    for (int e = tid; e < Cc * Dd / 4; e += 256) {
        const int r = e >> 5, c4 = e & 31;
        float4 kk = ((float4*)&sK[r][0])[c4];
        const float nk = sNk[r];
        kk.x *= nk; kk.y *= nk; kk.z *= nk; kk.w *= nk;
        ((float4*)&sK[r][0])[c4] = kk;
    }
    __syncthreads();

    // ---- wave-specialized phase ----
    const int wid = tid >> 6;
    const int lc = tid & 31;
    const int lh = (tid >> 5) & 1;
    const size_t cbase = (size_t)blk * Cc * Dd;
    const size_t abase = (size_t)blk * Cc * Cc;

    if (wid == 0) {
        // A[i][j] = beta_i * <k^_i, k^_j> via 3-term split MFMA
        f32x16 D, D2;
        #pragma unroll
        for (int r = 0; r < 16; ++r) { D[r] = 0.f; D2[r] = 0.f; }
        #pragma unroll
        for (int ks = 0; ks < 8; ++ks) {
            const float4 a = ((const float4*)&sK[lc][0])[4 * ks + 2 * lh];
            const float4 b = ((const float4*)&sK[lc][0])[4 * ks + 2 * lh + 1];
            bf16x8 hi, lo;
            split8(a, b, hi, lo);
            D  = __builtin_amdgcn_mfma_f32_32x32x16_bf16(hi, hi, D,  0, 0, 0);
            D2 = __builtin_amdgcn_mfma_f32_32x32x16_bf16(hi, lo, D2, 0, 0, 0);
            D2 = __builtin_amdgcn_mfma_f32_32x32x16_bf16(lo, hi, D2, 0, 0, 0);
        }
        #pragma unroll
        for (int r = 0; r < 16; ++r) {
            const int row = (r & 3) + 8 * (r >> 2) + 4 * lh;
            sA[row][lc] = (D[r] + D2[r]) * sBeta[row];
        }
        asm volatile("s_waitcnt lgkmcnt(0)" ::: "memory");
        __builtin_amdgcn_sched_barrier(0);

        // in-register forward substitution: lane lc owns column lc of inv
        float inv[Cc];
        #pragma unroll
        for (int m = 0; m < Cc; ++m) inv[m] = (m == lc) ? 1.f : 0.f;
        #pragma unroll
        for (int i = 1; i < Cc; ++i) {
            float s = 0.f;
            #pragma unroll
            for (int m = 0; m < i; ++m) s += sA[i][m] * inv[m];
            inv[i] = (lc == i) ? 1.f : -s;
        }
        if (lh == 0) {
            #pragma unroll
            for (int m = 0; m < Cc; ++m) sInv[m][lc] = inv[m];
        }
    } else if (wid == 1) {
        // attn = tril(q^ @ k^T) via 3-term split MFMA; write bf16 frag-major
        const float nq = sNq[lc];
        const float* qrow = q + base + (size_t)lc * Dd;
        f32x16 D, D2;
        #pragma unroll
        for (int r = 0; r < 16; ++r) { D[r] = 0.f; D2[r] = 0.f; }
        #pragma unroll
        for (int ks = 0; ks < 8; ++ks) {
            float4 a = ((const float4*)qrow)[4 * ks + 2 * lh];
            float4 b = ((const float4*)qrow)[4 * ks + 2 * lh + 1];
            a.x *= nq; a.y *= nq; a.z *= nq; a.w *= nq;
            b.x *= nq; b.y *= nq; b.z *= nq; b.w *= nq;
            bf16x8 hiQ, loQ;
            split8(a, b, hiQ, loQ);
            const float4 ka = ((const float4*)&sK[lc][0])[4 * ks + 2 * lh];
            const float4 kb2 = ((const float4*)&sK[lc][0])[4 * ks + 2 * lh + 1];
            bf16x8 hiK, loK;
            split8(ka, kb2, hiK, loK);
            D  = __builtin_amdgcn_mfma_f32_32x32x16_bf16(hiQ, hiK, D,  0, 0, 0);
            D2 = __builtin_amdgcn_mfma_f32_32x32x16_bf16(hiQ, loK, D2, 0, 0, 0);
            D2 = __builtin_amdgcn_mfma_f32_32x32x16_bf16(loQ, hiK, D2, 0, 0, 0);
        }
        #pragma unroll
        for (int r = 0; r < 16; ++r) {
            const int row = (r & 3) + 8 * (r >> 2) + 4 * lh;
            const float val = (lc <= row) ? (D[r] + D2[r]) : 0.f;
            wsAttnb[abase + ((lc >> 3) << 8) + (row << 3) + (lc & 7)] =
                f2bf(val);
        }
    } else {
        // waves 2-3: Ktb (k^ transposed frag-major) + Qnb (q^ frag-major)
        const int t = tid - 128;   // 0..127
        #pragma unroll
        for (int it = 0; it < 4; ++it) {
            const int g = t + it * 128;          // 0..511
            const int B = g >> 5, ddl = g & 31;
            const int dd = ((B >> 2) << 5) + ddl;
            const int cc0 = (B & 3) << 3;
            bf16x8 pk;
            #pragma unroll
            for (int j = 0; j < 8; ++j) pk[j] = f2bf(sK[cc0 + j][dd]);
            ((bf16x8*)(wsKtb + cbase))[g] = pk;
        }
        if constexpr (QNB) {
            #pragma unroll
            for (int it = 0; it < 4; ++it) {
                const int g = t + it * 128;      // 0..511
                const int c = g & 31;
                const int dd0 = (g >> 5) << 3;
                const float nq = sNq[c];
                const float4 a =
                    ((const float4*)(q + base + (size_t)c * Dd + dd0))[0];
                const float4 b =
                    ((const float4*)(q + base + (size_t)c * Dd + dd0))[1];
                bf16x8 pk;
                pk[0] = f2bf(a.x * nq); pk[1] = f2bf(a.y * nq);
                pk[2] = f2bf(a.z * nq); pk[3] = f2bf(a.w * nq);
                pk[4] = f2bf(b.x * nq); pk[5] = f2bf(b.y * nq);
                pk[6] = f2bf(b.z * nq); pk[7] = f2bf(b.w * nq);
                ((bf16x8*)(wsQnb + cbase))[g] = pk;
            }
        }
    }
    __syncthreads();

    // ---- u = inv @ (beta v) fp32 ; Wb = -(inv @ (beta k^)) bf16 ----
    {
        const int c = tid >> 3, g = tid & 7, dd0 = g * 16;
        float4 u0{}, u1{}, u2{}, u3{}, w0{}, w1{}, w2{}, w3{};
        for (int f = 0; f <= c; ++f) {
            const float ivb = sInv[c][f] * sBeta[f];
            const float4* vr = (const float4*)(v + base + (size_t)f * Dd + dd0);
            const float4* kr = (const float4*)&sK[f][dd0];
            fma4(u0, ivb, vr[0]); fma4(u1, ivb, vr[1]);
            fma4(u2, ivb, vr[2]); fma4(u3, ivb, vr[3]);
            fma4(w0, ivb, kr[0]); fma4(w1, ivb, kr[1]);
            fma4(w2, ivb, kr[2]); fma4(w3, ivb, kr[3]);
        }
        float* up = wsU + cbase + (size_t)c * Dd + dd0;
        ((float4*)up)[0] = u0; ((float4*)up)[1] = u1;
        ((float4*)up)[2] = u2; ((float4*)up)[3] = u3;
        bf16x8 p0, p1;
        p0[0] = f2bf(-w0.x); p0[1] = f2bf(-w0.y); p0[2] = f2bf(-w0.z);
        p0[3] = f2bf(-w0.w); p0[4] = f2bf(-w1.x); p0[5] = f2bf(-w1.y);
        p0[6] = f2bf(-w1.z); p0[7] = f2bf(-w1.w);
        p1[0] = f2bf(-w2.x); p1[1] = f2bf(-w2.y); p1[2] = f2bf(-w2.z);
        p1[3] = f2bf(-w2.w); p1[4] = f2bf(-w3.x); p1[5] = f2bf(-w3.y);
        p1[6] = f2bf(-w3.z); p1[7] = f2bf(-w3.w);
        ((bf16x8*)(wsWb + cbase))[(2 * g) * 32 + c] = p0;
        ((bf16x8*)(wsWb + cbase))[(2 * g + 1) * 32 + c] = p1;
    }
}

// ---------------------------------------------------------------------------
// Kernel 2: MFMA scan. 64 blocks x 64 threads (1 wave/CU). Unchanged (R6).
// ---------------------------------------------------------------------------
template <bool QNB>
__device__ __forceinline__ void stage(
    char* lbuf, int bh, int ch, int colBase, int lane,
    const short* __restrict__ wsWb, const short* __restrict__ wsKtb,
    const short* __restrict__ wsAttnb, const short* __restrict__ wsQnb,
    const float* __restrict__ wsU)
{
    const size_t cb = (size_t)(bh * NC + ch) * (Cc * Dd);
    const size_t ab = (size_t)(bh * NC + ch) * (Cc * Cc);
    const char* srcW = (const char*)(wsWb + cb);
    const char* srcK = (const char*)(wsKtb + cb);
    const char* srcA = (const char*)(wsAttnb + ab);
    const int l16 = lane * 16;
    #pragma unroll
    for (int g = 0; g < 8; ++g)
        gl_lds16(srcW + g * 1024 + l16, lbuf + g * 1024);
    #pragma unroll
    for (int g = 0; g < 8; ++g)
        gl_lds16(srcK + g * 1024 + l16, lbuf + 8192 + g * 1024);
    if constexpr (QNB) {
        const char* srcQ = (const char*)(wsQnb + cb);
        #pragma unroll
        for (int g = 0; g < 8; ++g)
            gl_lds16(srcQ + g * 1024 + l16, lbuf + 16384 + g * 1024);
    }
    #pragma unroll
    for (int g = 0; g < 2; ++g)
        gl_lds16(srcA + g * 1024 + l16, lbuf + 24576 + g * 1024);
    #pragma unroll
    for (int g = 0; g < 4; ++g) {
        const int row = g * 8 + (lane >> 3);
        const float* srcU = wsU + cb + (size_t)row * Dd + colBase + (lane & 7) * 4;
        gl_lds16(srcU, lbuf + 26624 + g * 1024);
    }
}
// loads per stage: QNB ? 30 : 22

template <bool QNB>
__device__ __forceinline__ void compute_chunk(
    const char* lbuf, int bh, int ch, int colBase, int c, int h,
    const float* __restrict__ q, const float* __restrict__ wsNq,
    f32x16& S0, f32x16& S1, f32x16& S2, f32x16& S3, float* __restrict__ out)
{
    const bf16x8* Wf = (const bf16x8*)(lbuf);
    const bf16x8* Kf = (const bf16x8*)(lbuf + 8192);
    const bf16x8* Qf = (const bf16x8*)(lbuf + 16384);
    const bf16x8* Af = (const bf16x8*)(lbuf + 24576);
    const float*  Uf = (const float*)(lbuf + 26624);

    bf16x8 qa[8];
    if constexpr (QNB) {
        #pragma unroll
        for (int ks = 0; ks < 8; ++ks) qa[ks] = Qf[(2 * ks + h) * 32 + c];
    } else {
        const size_t qb = (size_t)(bh * Ll + ch * Cc) * Dd;
        const float rq = wsNq[bh * Ll + ch * Cc + c];
        #pragma unroll
        for (int ks = 0; ks < 8; ++ks) {
            const float4 a = ((const float4*)(q + qb))[c * 32 + 4 * ks + 2 * h];
            const float4 b = ((const float4*)(q + qb))[c * 32 + 4 * ks + 2 * h + 1];
            union { unsigned u[4]; bf16x8 v; } t;
            t.u[0] = cvt_pk_bf16(a.x * rq, a.y * rq);
            t.u[1] = cvt_pk_bf16(a.z * rq, a.w * rq);
            t.u[2] = cvt_pk_bf16(b.x * rq, b.y * rq);
            t.u[3] = cvt_pk_bf16(b.z * rq, b.w * rq);
            qa[ks] = t.v;
        }
    }

    f32x16 Ua, Ub, O1, O2;
    #pragma unroll
    for (int r = 0; r < 16; ++r) {
        const int row = (r & 3) + 8 * (r >> 2) + 4 * h;
        Ua[r] = Uf[row * 32 + c];
        Ub[r] = 0.f; O1[r] = 0.f; O2[r] = 0.f;
    }

    #pragma unroll
    for (int ks = 0; ks < 8; ++ks) {
        const f32x16& T = (ks < 2) ? S0 : (ks < 4) ? S1 : (ks < 6) ? S2 : S3;
        const bf16x8 sB = mk_bop(T, ks & 1);
        const bf16x8 wA = Wf[(2 * ks + h) * 32 + c];
        if (ks < 4)
            Ua = __builtin_amdgcn_mfma_f32_32x32x16_bf16(wA, sB, Ua, 0, 0, 0);
        else
            Ub = __builtin_amdgcn_mfma_f32_32x32x16_bf16(wA, sB, Ub, 0, 0, 0);
        if (ks & 1)
            O2 = __builtin_amdgcn_mfma_f32_32x32x16_bf16(qa[ks], sB, O2, 0, 0, 0);
        else
            O1 = __builtin_amdgcn_mfma_f32_32x32x16_bf16(qa[ks], sB, O1, 0, 0, 0);
    }

    f32x16 Us;
    #pragma unroll
    for (int r = 0; r < 16; ++r) Us[r] = Ua[r] + Ub[r];

    const bf16x8 uB0 = mk_bop(Us, 0);
    const bf16x8 uB1 = mk_bop(Us, 1);

    // S updates first — they gate the next chunk's sB builds.
    S0 = __builtin_amdgcn_mfma_f32_32x32x16_bf16(Kf[(0 + h) * 32 + c],  uB0, S0, 0, 0, 0);
    S0 = __builtin_amdgcn_mfma_f32_32x32x16_bf16(Kf[(2 + h) * 32 + c],  uB1, S0, 0, 0, 0);
    S1 = __builtin_amdgcn_mfma_f32_32x32x16_bf16(Kf[(4 + h) * 32 + c],  uB0, S1, 0, 0, 0);
    S1 = __builtin_amdgcn_mfma_f32_32x32x16_bf16(Kf[(6 + h) * 32 + c],  uB1, S1, 0, 0, 0);
    S2 = __builtin_amdgcn_mfma_f32_32x32x16_bf16(Kf[(8 + h) * 32 + c],  uB0, S2, 0, 0, 0);
    S2 = __builtin_amdgcn_mfma_f32_32x32x16_bf16(Kf[(10 + h) * 32 + c], uB1, S2, 0, 0, 0);
    S3 = __builtin_amdgcn_mfma_f32_32x32x16_bf16(Kf[(12 + h) * 32 + c], uB0, S3, 0, 0, 0);
    S3 = __builtin_amdgcn_mfma_f32_32x32x16_bf16(Kf[(14 + h) * 32 + c], uB1, S3, 0, 0, 0);

    O1 = __builtin_amdgcn_mfma_f32_32x32x16_bf16(Af[(0 + h) * 32 + c], uB0, O1, 0, 0, 0);
    O2 = __builtin_amdgcn_mfma_f32_32x32x16_bf16(Af[(2 + h) * 32 + c], uB1, O2, 0, 0, 0);

    const size_t qb = (size_t)(bh * Ll + ch * Cc) * Dd;
    #pragma unroll
    for (int r = 0; r < 16; ++r) {
        const int row = (r & 3) + 8 * (r >> 2) + 4 * h;
        out[qb + (size_t)row * Dd + colBase + c] = O1[r] + O2[r];
    }
}

template <bool QNB>
__global__ __launch_bounds__(64, 1) void scan_kernel(
    const float* __restrict__ q, const float* __restrict__ wsU,
    const short* __restrict__ wsWb, const short* __restrict__ wsKtb,
    const short* __restrict__ wsAttnb, const short* __restrict__ wsQnb,
    const float* __restrict__ wsNq, float* __restrict__ out)
{
    __shared__ __attribute__((aligned(16))) char lds[2][SLAB];

    const int lane = threadIdx.x;
    const int h = lane >> 5;
    const int c = lane & 31;
    const int bh = blockIdx.x;
    const int colBase = blockIdx.y * 32;

    f32x16 S0, S1, S2, S3;
    #pragma unroll
    for (int r = 0; r < 16; ++r) { S0[r]=0.f; S1[r]=0.f; S2[r]=0.f; S3[r]=0.f; }

    stage<QNB>(lds[0], bh, 0, colBase, lane, wsWb, wsKtb, wsAttnb, wsQnb, wsU);
    for (int ch = 0; ch < NC; ++ch) {
        if (ch + 1 < NC) {
            stage<QNB>(lds[(ch + 1) & 1], bh, ch + 1, colBase, lane,
                       wsWb, wsKtb, wsAttnb, wsQnb, wsU);
            if constexpr (QNB) WAITVM(30); else WAITVM(22);
        } else {
            WAITVM(0);
        }
        compute_chunk<QNB>(lds[ch & 1], bh, ch, colBase, c, h, q, wsNq,
                           S0, S1, S2, S3, out);
    }

    // S_final -> d_out tail
    const size_t soff = (size_t)Bb * Hh * Ll * Dd;
    #pragma unroll
    for (int t = 0; t < 4; ++t) {
        const f32x16& T = (t == 0) ? S0 : (t == 1) ? S1 : (t == 2) ? S2 : S3;
        #pragma unroll
        for (int r = 0; r < 16; ++r) {
            const int row = 32 * t + (r & 3) + 8 * (r >> 2) + 4 * h;
            out[soff + (size_t)bh * Dd * Dd + (size_t)row * Dd + colBase + c] =
                T[r];
        }
    }
}

extern "C" void kernel_launch(void* const* d_in, const int* in_sizes, int n_in,
                              void* d_out, int out_size, void* d_ws,
                              size_t ws_size, hipStream_t stream) {
    const float* q    = (const float*)d_in[0];
    const float* k    = (const float*)d_in[1];
    const float* v    = (const float*)d_in[2];
    const float* beta = (const float*)d_in[3];
    float* out = (float*)d_out;

    const size_t nQK = (size_t)BHn * Ll * Dd;          // 8,388,608
    float* wsU    = (float*)d_ws;                      // fp32, 32 MB
    float* wsNq   = wsU + nQK;                         // fp32, 0.25 MB
    short* wsWb   = (short*)(wsNq + (size_t)BHn * Ll); // bf16, 16 MB
    short* wsKtb  = wsWb + nQK;                        // bf16, 16 MB
    short* wsAttnb = wsKtb + nQK;                      // bf16, 4 MB
    short* wsQnb  = wsAttnb + (size_t)BHn * NC * Cc * Cc; // bf16, 16 MB (opt)
    const size_t need_qnb = (size_t)((char*)(wsQnb + nQK) - (char*)d_ws);

    if (ws_size >= need_qnb) {
        prep_kernel<true><<<dim3(BHn * NC), 256, 0, stream>>>(
            q, k, v, beta, wsU, wsNq, wsWb, wsKtb, wsAttnb, wsQnb);
        scan_kernel<true><<<dim3(BHn, 4), 64, 0, stream>>>(
            q, wsU, wsWb, wsKtb, wsAttnb, wsQnb, wsNq, out);
    } else {
        prep_kernel<false><<<dim3(BHn * NC), 256, 0, stream>>>(
            q, k, v, beta, wsU, wsNq, wsWb, wsKtb, wsAttnb, wsQnb);
        scan_kernel<false><<<dim3(BHn, 4), 64, 0, stream>>>(
            q, wsU, wsWb, wsKtb, wsAttnb, wsQnb, wsNq, out);
    }
}

// Round 4
// 349.721 us; speedup vs baseline: 1.7844x; 1.0103x over previous
//
#include <hip/hip_runtime.h>

// DeltaNet chunkwise delta rule. b=2,h=8,L=4096,d=128,chunk=32.
// R8: scan pipeline made compiler-legible.
//  - 3 NAMED 20KB LDS slabs (Wb+Ktb+U), loop unrolled x6 so slab choice is
//    compile-time -> LLVM's per-object LDS-DMA tracking emits PRECISE waits
//    (R6/R7's lds[2][SLAB] with runtime index forced conservative drains).
//  - depth-2 global_load_lds prefetch; NO manual vmcnt (compiler's is exact).
//  - qa/at prefetched into registers (20 VGPR dbuf), precise vmcnt.
//  - U written by prep in C-fragment order [colblk][rh][col]: scan U reads
//    are conflict-free ds_read_b32 (bank=c, 2-way across h = free), staging
//    stays linear for global_load_lds.

#define Bb 2
#define Hh 8
#define Ll 4096
#define Dd 128
#define DP (Dd + 4)
#define Cc 32
#define CP2 33
#define NC (Ll / Cc)       // 128 chunks
#define BHn (Bb * Hh)      // 16 heads

// scan slab layout (bytes): 0: Wb frag-major [16][32] bf16x8 = 8192
//                           8192: Ktb frag-major [16][32] bf16x8 = 8192
//                           16384: U slice [32 rh][32 col] f32 = 4096
#define SLAB 20480

typedef float  f32x16 __attribute__((ext_vector_type(16)));
typedef short  bf16x8 __attribute__((ext_vector_type(8)));

__device__ __forceinline__ short f2bf(float x) {
    union { float f; unsigned u; } a; a.f = x;
    const unsigned r = a.u + 0x7FFFu + ((a.u >> 16) & 1u);  // RNE
    return (short)(r >> 16);
}

__device__ __forceinline__ float bf2f(short h) {
    union { unsigned u; float f; } t;
    t.u = ((unsigned)(unsigned short)h) << 16;
    return t.f;
}

__device__ __forceinline__ unsigned cvt_pk_bf16(float lo, float hi) {
    unsigned r;
    asm("v_cvt_pk_bf16_f32 %0, %1, %2" : "=v"(r) : "v"(lo), "v"(hi));
    return r;
}

// C-layout quadrant -> MFMA B-operand fragment for K=16 slice m, via
// v_cvt_pk_bf16_f32 + v_permlane32_swap (VALU only). Proven R5-R7.
__device__ __forceinline__ bf16x8 mk_bop(const f32x16& T, int m) {
    const int o = 8 * m;
    const unsigned a01 = cvt_pk_bf16(T[o + 0], T[o + 1]);
    const unsigned a23 = cvt_pk_bf16(T[o + 2], T[o + 3]);
    const unsigned b01 = cvt_pk_bf16(T[o + 4], T[o + 5]);
    const unsigned b23 = cvt_pk_bf16(T[o + 6], T[o + 7]);
    const auto r0 = __builtin_amdgcn_permlane32_swap(a01, b01, false, false);
    const auto r1 = __builtin_amdgcn_permlane32_swap(a23, b23, false, false);
    union { unsigned u[4]; bf16x8 v; } out;
    out.u[0] = r0[0]; out.u[1] = r1[0]; out.u[2] = r0[1]; out.u[3] = r1[1];
    return out.v;
}

__device__ __forceinline__ void gl_lds16(const void* gsrc, void* ldst) {
    __builtin_amdgcn_global_load_lds(
        (const __attribute__((address_space(1))) unsigned int*)gsrc,
        (__attribute__((address_space(3))) unsigned int*)ldst, 16, 0, 0);
}

// split 8 fp32 into bf16 hi + bf16 residual lo (3-term split-MFMA inputs)
__device__ __forceinline__ void split8(const float4& a, const float4& b,
                                       bf16x8& hi, bf16x8& lo) {
    const float x[8] = {a.x, a.y, a.z, a.w, b.x, b.y, b.z, b.w};
    #pragma unroll
    for (int j = 0; j < 8; ++j) {
        const short hs = f2bf(x[j]);
        hi[j] = hs;
        lo[j] = f2bf(x[j] - bf2f(hs));
    }
}

__device__ __forceinline__ void fma4(float4& acc, float s, const float4& x) {
    acc.x += s * x.x; acc.y += s * x.y; acc.z += s * x.z; acc.w += s * x.w;
}

// ---------------------------------------------------------------------------
// Kernel 1: per-(head,chunk) precompute. 2048 blocks x 256. (R7 + new U order)
// ---------------------------------------------------------------------------
template <bool QNB>
__global__ __launch_bounds__(256, 4) void prep_kernel(
    const float* __restrict__ q, const float* __restrict__ k,
    const float* __restrict__ v, const float* __restrict__ beta,
    float* __restrict__ wsU, float* __restrict__ wsNq,
    short* __restrict__ wsWb, short* __restrict__ wsKtb,
    short* __restrict__ wsAttnb, short* __restrict__ wsQnb)
{
    __shared__ float sK[Cc][DP];          // 16.9 KB (normalized k)
    __shared__ float sA[Cc][CP2];         // 4.2 KB
    __shared__ float sInv[Cc][CP2];       // 4.2 KB
    __shared__ float sBeta[Cc], sNk[Cc], sNq[Cc];

    const int tid = threadIdx.x;
    const int blk = blockIdx.x;          // bh*NC + ch
    const int bh = blk / NC;
    const int ch = blk % NC;
    const size_t base = (size_t)(bh * Ll + ch * Cc) * Dd;

    // ---- load k -> LDS; beta ----
    for (int e = tid; e < Cc * Dd / 4; e += 256) {
        const int r = e >> 5, c4 = e & 31;
        ((float4*)&sK[r][0])[c4] = ((const float4*)(k + base))[e];
    }
    if (tid < Cc) sBeta[tid] = beta[bh * Ll + ch * Cc + tid];
    __syncthreads();

    // ---- row norms: rows 0..31 = k (LDS), 32..63 = q (global) ----
    {
        const int row = tid >> 2, part = tid & 3;
        float s = 0.f;
        if (row < Cc) {
            const float4* src = (const float4*)&sK[row][0];
            #pragma unroll
            for (int j = 0; j < 8; ++j) {
                const float4 t = src[part + j * 4];
                s += t.x * t.x + t.y * t.y + t.z * t.z + t.w * t.w;
            }
        } else {
            const float4* src =
                (const float4*)(q + base + (size_t)(row - Cc) * Dd);
            #pragma unroll
            for (int j = 0; j < 8; ++j) {
                const float4 t = src[part + j * 4];
                s += t.x * t.x + t.y * t.y + t.z * t.z + t.w * t.w;
            }
        }
        s += __shfl_xor(s, 1);
        s += __shfl_xor(s, 2);
        if (part == 0) {
            const float r = 1.0f / sqrtf(s);
            if (row < Cc) sNk[row] = r; else sNq[row - Cc] = r;
        }
    }
    __syncthreads();

    if (tid < Cc) wsNq[bh * Ll + ch * Cc + tid] = sNq[tid];

    // ---- scale k rows in place ----
    for (int e = tid; e < Cc * Dd / 4; e += 256) {
        const int r = e >> 5, c4 = e & 31;
        float4 kk = ((float4*)&sK[r][0])[c4];
        const float nk = sNk[r];
        kk.x *= nk; kk.y *= nk; kk.z *= nk; kk.w *= nk;
        ((float4*)&sK[r][0])[c4] = kk;
    }
    __syncthreads();

    // ---- wave-specialized phase ----
    const int wid = tid >> 6;
    const int lc = tid & 31;
    const int lh = (tid >> 5) & 1;
    const size_t cbase = (size_t)blk * Cc * Dd;
    const size_t abase = (size_t)blk * Cc * Cc;

    if (wid == 0) {
        // A[i][j] = beta_i * <k^_i, k^_j> via 3-term split MFMA
        f32x16 D, D2;
        #pragma unroll
        for (int r = 0; r < 16; ++r) { D[r] = 0.f; D2[r] = 0.f; }
        #pragma unroll
        for (int ks = 0; ks < 8; ++ks) {
            const float4 a = ((const float4*)&sK[lc][0])[4 * ks + 2 * lh];
            const float4 b = ((const float4*)&sK[lc][0])[4 * ks + 2 * lh + 1];
            bf16x8 hi, lo;
            split8(a, b, hi, lo);
            D  = __builtin_amdgcn_mfma_f32_32x32x16_bf16(hi, hi, D,  0, 0, 0);
            D2 = __builtin_amdgcn_mfma_f32_32x32x16_bf16(hi, lo, D2, 0, 0, 0);
            D2 = __builtin_amdgcn_mfma_f32_32x32x16_bf16(lo, hi, D2, 0, 0, 0);
        }
        #pragma unroll
        for (int r = 0; r < 16; ++r) {
            const int row = (r & 3) + 8 * (r >> 2) + 4 * lh;
            sA[row][lc] = (D[r] + D2[r]) * sBeta[row];
        }
        asm volatile("s_waitcnt lgkmcnt(0)" ::: "memory");
        __builtin_amdgcn_sched_barrier(0);

        // in-register forward substitution: lane lc owns column lc of inv
        float inv[Cc];
        #pragma unroll
        for (int m = 0; m < Cc; ++m) inv[m] = (m == lc) ? 1.f : 0.f;
        #pragma unroll
        for (int i = 1; i < Cc; ++i) {
            float s = 0.f;
            #pragma unroll
            for (int m = 0; m < i; ++m) s += sA[i][m] * inv[m];
            inv[i] = (lc == i) ? 1.f : -s;
        }
        if (lh == 0) {
            #pragma unroll
            for (int m = 0; m < Cc; ++m) sInv[m][lc] = inv[m];
        }
    } else if (wid == 1) {
        // attn = tril(q^ @ k^T) via 3-term split MFMA; write bf16 frag-major
        const float nq = sNq[lc];
        const float* qrow = q + base + (size_t)lc * Dd;
        f32x16 D, D2;
        #pragma unroll
        for (int r = 0; r < 16; ++r) { D[r] = 0.f; D2[r] = 0.f; }
        #pragma unroll
        for (int ks = 0; ks < 8; ++ks) {
            float4 a = ((const float4*)qrow)[4 * ks + 2 * lh];
            float4 b = ((const float4*)qrow)[4 * ks + 2 * lh + 1];
            a.x *= nq; a.y *= nq; a.z *= nq; a.w *= nq;
            b.x *= nq; b.y *= nq; b.z *= nq; b.w *= nq;
            bf16x8 hiQ, loQ;
            split8(a, b, hiQ, loQ);
            const float4 ka = ((const float4*)&sK[lc][0])[4 * ks + 2 * lh];
            const float4 kb2 = ((const float4*)&sK[lc][0])[4 * ks + 2 * lh + 1];
            bf16x8 hiK, loK;
            split8(ka, kb2, hiK, loK);
            D  = __builtin_amdgcn_mfma_f32_32x32x16_bf16(hiQ, hiK, D,  0, 0, 0);
            D2 = __builtin_amdgcn_mfma_f32_32x32x16_bf16(hiQ, loK, D2, 0, 0, 0);
            D2 = __builtin_amdgcn_mfma_f32_32x32x16_bf16(loQ, hiK, D2, 0, 0, 0);
        }
        #pragma unroll
        for (int r = 0; r < 16; ++r) {
            const int row = (r & 3) + 8 * (r >> 2) + 4 * lh;
            const float val = (lc <= row) ? (D[r] + D2[r]) : 0.f;
            wsAttnb[abase + ((lc >> 3) << 8) + (row << 3) + (lc & 7)] =
                f2bf(val);
        }
    } else {
        // waves 2-3: Ktb (k^ transposed frag-major) + Qnb (q^ frag-major)
        const int t = tid - 128;   // 0..127
        #pragma unroll
        for (int it = 0; it < 4; ++it) {
            const int g = t + it * 128;          // 0..511
            const int B = g >> 5, ddl = g & 31;
            const int dd = ((B >> 2) << 5) + ddl;
            const int cc0 = (B & 3) << 3;
            bf16x8 pk;
            #pragma unroll
            for (int j = 0; j < 8; ++j) pk[j] = f2bf(sK[cc0 + j][dd]);
            ((bf16x8*)(wsKtb + cbase))[g] = pk;
        }
        if constexpr (QNB) {
            #pragma unroll
            for (int it = 0; it < 4; ++it) {
                const int g = t + it * 128;      // 0..511
                const int c = g & 31;
                const int dd0 = (g >> 5) << 3;
                const float nq = sNq[c];
                const float4 a =
                    ((const float4*)(q + base + (size_t)c * Dd + dd0))[0];
                const float4 b =
                    ((const float4*)(q + base + (size_t)c * Dd + dd0))[1];
                bf16x8 pk;
                pk[0] = f2bf(a.x * nq); pk[1] = f2bf(a.y * nq);
                pk[2] = f2bf(a.z * nq); pk[3] = f2bf(a.w * nq);
                pk[4] = f2bf(b.x * nq); pk[5] = f2bf(b.y * nq);
                pk[6] = f2bf(b.z * nq); pk[7] = f2bf(b.w * nq);
                ((bf16x8*)(wsQnb + cbase))[g] = pk;
            }
        }
    }
    __syncthreads();

    // ---- u = inv @ (beta v) fp32 (C-frag order); Wb = -(inv @ (beta k^)) ----
    {
        const int c = tid >> 3, g = tid & 7, dd0 = g * 16;
        float4 u0{}, u1{}, u2{}, u3{}, w0{}, w1{}, w2{}, w3{};
        for (int f = 0; f <= c; ++f) {
            const float ivb = sInv[c][f] * sBeta[f];
            const float4* vr = (const float4*)(v + base + (size_t)f * Dd + dd0);
            const float4* kr = (const float4*)&sK[f][dd0];
            fma4(u0, ivb, vr[0]); fma4(u1, ivb, vr[1]);
            fma4(u2, ivb, vr[2]); fma4(u3, ivb, vr[3]);
            fma4(w0, ivb, kr[0]); fma4(w1, ivb, kr[1]);
            fma4(w2, ivb, kr[2]); fma4(w3, ivb, kr[3]);
        }
        // U in C-frag order: [colblk 4][rh 32][col 32] per chunk
        const int rh = (c & 3) + ((c >> 3) << 2) + (((c >> 2) & 1) << 4);
        const float uu[16] = {u0.x, u0.y, u0.z, u0.w, u1.x, u1.y, u1.z, u1.w,
                              u2.x, u2.y, u2.z, u2.w, u3.x, u3.y, u3.z, u3.w};
        #pragma unroll
        for (int j = 0; j < 16; ++j) {
            const int dd = dd0 + j;
            wsU[cbase + ((dd >> 5) << 10) + (rh << 5) + (dd & 31)] = uu[j];
        }
        bf16x8 p0, p1;
        p0[0] = f2bf(-w0.x); p0[1] = f2bf(-w0.y); p0[2] = f2bf(-w0.z);
        p0[3] = f2bf(-w0.w); p0[4] = f2bf(-w1.x); p0[5] = f2bf(-w1.y);
        p0[6] = f2bf(-w1.z); p0[7] = f2bf(-w1.w);
        p1[0] = f2bf(-w2.x); p1[1] = f2bf(-w2.y); p1[2] = f2bf(-w2.z);
        p1[3] = f2bf(-w2.w); p1[4] = f2bf(-w3.x); p1[5] = f2bf(-w3.y);
        p1[6] = f2bf(-w3.z); p1[7] = f2bf(-w3.w);
        ((bf16x8*)(wsWb + cbase))[(2 * g) * 32 + c] = p0;
        ((bf16x8*)(wsWb + cbase))[(2 * g + 1) * 32 + c] = p1;
    }
}

// ---------------------------------------------------------------------------
// Kernel 2: MFMA scan. 64 blocks x 64 threads. 3 named slabs, depth-2.
// ---------------------------------------------------------------------------
struct RegOps { bf16x8 qa[8]; bf16x8 at[2]; };

template <bool QNB>
__device__ __forceinline__ void load_regs(
    RegOps& R, int bh, int ch, int c, int h,
    const short* __restrict__ wsQnb, const short* __restrict__ wsAttnb)
{
    const size_t cb = (size_t)(bh * NC + ch) * (Cc * Dd);
    const size_t ab = (size_t)(bh * NC + ch) * (Cc * Cc);
    if constexpr (QNB) {
        #pragma unroll
        for (int ks = 0; ks < 8; ++ks)
            R.qa[ks] = ((const bf16x8*)(wsQnb + cb))[(2 * ks + h) * 32 + c];
    }
    R.at[0] = ((const bf16x8*)(wsAttnb + ab))[(0 + h) * 32 + c];
    R.at[1] = ((const bf16x8*)(wsAttnb + ab))[(2 + h) * 32 + c];
}

__device__ __forceinline__ void stage_slab(
    char* slab, int bh, int ch, int colBase, int lane,
    const short* __restrict__ wsWb, const short* __restrict__ wsKtb,
    const float* __restrict__ wsU)
{
    const size_t cb = (size_t)(bh * NC + ch) * (Cc * Dd);
    const char* srcW = (const char*)(wsWb + cb);
    const char* srcK = (const char*)(wsKtb + cb);
    const int l16 = lane * 16;
    #pragma unroll
    for (int g = 0; g < 8; ++g)
        gl_lds16(srcW + g * 1024 + l16, slab + g * 1024);
    #pragma unroll
    for (int g = 0; g < 8; ++g)
        gl_lds16(srcK + g * 1024 + l16, slab + 8192 + g * 1024);
    const float* srcU = wsU + cb + (colBase << 5);
    #pragma unroll
    for (int g = 0; g < 4; ++g)
        gl_lds16(srcU + g * 256 + lane * 4, slab + 16384 + g * 1024);
}
// 20 loads per stage

template <bool QNB>
__device__ __forceinline__ void step(
    int ch, char* slab, char* slab2, bool dostage,
    const RegOps& cur, RegOps& nxt,
    int bh, int colBase, int c, int h, int lane,
    const float* __restrict__ q, const float* __restrict__ wsNq,
    const short* __restrict__ wsWb, const short* __restrict__ wsKtb,
    const short* __restrict__ wsAttnb, const short* __restrict__ wsQnb,
    const float* __restrict__ wsU,
    f32x16& S0, f32x16& S1, f32x16& S2, f32x16& S3, float* __restrict__ out)
{
    // register prefetch for chunk ch+1 (precise vmcnt by construction)
    const int chn = (ch + 1 < NC) ? ch + 1 : NC - 1;
    load_regs<QNB>(nxt, bh, chn, c, h, wsQnb, wsAttnb);

    const bf16x8* Wf = (const bf16x8*)slab;
    const bf16x8* Kf = (const bf16x8*)(slab + 8192);
    const float*  Uf = (const float*)(slab + 16384);

    bf16x8 qa[8];
    if constexpr (QNB) {
        #pragma unroll
        for (int ks = 0; ks < 8; ++ks) qa[ks] = cur.qa[ks];
    } else {
        const size_t qb = (size_t)(bh * Ll + ch * Cc) * Dd;
        const float rq = wsNq[bh * Ll + ch * Cc + c];
        #pragma unroll
        for (int ks = 0; ks < 8; ++ks) {
            const float4 a = ((const float4*)(q + qb))[c * 32 + 4 * ks + 2 * h];
            const float4 b = ((const float4*)(q + qb))[c * 32 + 4 * ks + 2 * h + 1];
            union { unsigned u[4]; bf16x8 v; } t;
            t.u[0] = cvt_pk_bf16(a.x * rq, a.y * rq);
            t.u[1] = cvt_pk_bf16(a.z * rq, a.w * rq);
            t.u[2] = cvt_pk_bf16(b.x * rq, b.y * rq);
            t.u[3] = cvt_pk_bf16(b.z * rq, b.w * rq);
            qa[ks] = t.v;
        }
    }

    f32x16 Ua, Ub, O1, O2;
    #pragma unroll
    for (int r = 0; r < 16; ++r) {
        Ua[r] = Uf[(r + 16 * h) * 32 + c];
        Ub[r] = 0.f; O1[r] = 0.f; O2[r] = 0.f;
    }

    #pragma unroll
    for (int ks = 0; ks < 8; ++ks) {
        const f32x16& T = (ks < 2) ? S0 : (ks < 4) ? S1 : (ks < 6) ? S2 : S3;
        const bf16x8 sB = mk_bop(T, ks & 1);
        const bf16x8 wA = Wf[(2 * ks + h) * 32 + c];
        if (ks < 4)
            Ua = __builtin_amdgcn_mfma_f32_32x32x16_bf16(wA, sB, Ua, 0, 0, 0);
        else
            Ub = __builtin_amdgcn_mfma_f32_32x32x16_bf16(wA, sB, Ub, 0, 0, 0);
        if (ks & 1)
            O2 = __builtin_amdgcn_mfma_f32_32x32x16_bf16(qa[ks], sB, O2, 0, 0, 0);
        else
            O1 = __builtin_amdgcn_mfma_f32_32x32x16_bf16(qa[ks], sB, O1, 0, 0, 0);
    }

    f32x16 Us;
    #pragma unroll
    for (int r = 0; r < 16; ++r) Us[r] = Ua[r] + Ub[r];

    const bf16x8 uB0 = mk_bop(Us, 0);
    const bf16x8 uB1 = mk_bop(Us, 1);

    // S updates first — they gate the next chunk's sB builds.
    S0 = __builtin_amdgcn_mfma_f32_32x32x16_bf16(Kf[(0 + h) * 32 + c],  uB0, S0, 0, 0, 0);
    S0 = __builtin_amdgcn_mfma_f32_32x32x16_bf16(Kf[(2 + h) * 32 + c],  uB1, S0, 0, 0, 0);
    S1 = __builtin_amdgcn_mfma_f32_32x32x16_bf16(Kf[(4 + h) * 32 + c],  uB0, S1, 0, 0, 0);
    S1 = __builtin_amdgcn_mfma_f32_32x32x16_bf16(Kf[(6 + h) * 32 + c],  uB1, S1, 0, 0, 0);
    S2 = __builtin_amdgcn_mfma_f32_32x32x16_bf16(Kf[(8 + h) * 32 + c],  uB0, S2, 0, 0, 0);
    S2 = __builtin_amdgcn_mfma_f32_32x32x16_bf16(Kf[(10 + h) * 32 + c], uB1, S2, 0, 0, 0);
    S3 = __builtin_amdgcn_mfma_f32_32x32x16_bf16(Kf[(12 + h) * 32 + c], uB0, S3, 0, 0, 0);
    S3 = __builtin_amdgcn_mfma_f32_32x32x16_bf16(Kf[(14 + h) * 32 + c], uB1, S3, 0, 0, 0);

    O1 = __builtin_amdgcn_mfma_f32_32x32x16_bf16(cur.at[0], uB0, O1, 0, 0, 0);
    O2 = __builtin_amdgcn_mfma_f32_32x32x16_bf16(cur.at[1], uB1, O2, 0, 0, 0);

    if (dostage)
        stage_slab(slab2, bh, ch + 2, colBase, lane, wsWb, wsKtb, wsU);

    const size_t qb = (size_t)(bh * Ll + ch * Cc) * Dd;
    #pragma unroll
    for (int r = 0; r < 16; ++r) {
        const int row = (r & 3) + 8 * (r >> 2) + 4 * h;
        out[qb + (size_t)row * Dd + colBase + c] = O1[r] + O2[r];
    }
}

template <bool QNB>
__global__ __launch_bounds__(64, 1) void scan_kernel(
    const float* __restrict__ q, const float* __restrict__ wsU,
    const short* __restrict__ wsWb, const short* __restrict__ wsKtb,
    const short* __restrict__ wsAttnb, const short* __restrict__ wsQnb,
    const float* __restrict__ wsNq, float* __restrict__ out)
{
    __shared__ __attribute__((aligned(16))) char sl0[SLAB];
    __shared__ __attribute__((aligned(16))) char sl1[SLAB];
    __shared__ __attribute__((aligned(16))) char sl2[SLAB];

    const int lane = threadIdx.x;
    const int h = lane >> 5;
    const int c = lane & 31;
    const int bh = blockIdx.x;
    const int colBase = blockIdx.y * 32;

    f32x16 S0, S1, S2, S3;
    #pragma unroll
    for (int r = 0; r < 16; ++r) { S0[r]=0.f; S1[r]=0.f; S2[r]=0.f; S3[r]=0.f; }

    RegOps R0, R1;
    stage_slab(sl0, bh, 0, colBase, lane, wsWb, wsKtb, wsU);
    stage_slab(sl1, bh, 1, colBase, lane, wsWb, wsKtb, wsU);
    load_regs<QNB>(R0, bh, 0, c, h, wsQnb, wsAttnb);

    #pragma unroll 1
    for (int it = 0; it < 21; ++it) {
        const int ch = it * 6;
        step<QNB>(ch + 0, sl0, sl2, true, R0, R1, bh, colBase, c, h, lane,
                  q, wsNq, wsWb, wsKtb, wsAttnb, wsQnb, wsU, S0, S1, S2, S3, out);
        step<QNB>(ch + 1, sl1, sl0, true, R1, R0, bh, colBase, c, h, lane,
                  q, wsNq, wsWb, wsKtb, wsAttnb, wsQnb, wsU, S0, S1, S2, S3, out);
        step<QNB>(ch + 2, sl2, sl1, true, R0, R1, bh, colBase, c, h, lane,
                  q, wsNq, wsWb, wsKtb, wsAttnb, wsQnb, wsU, S0, S1, S2, S3, out);
        step<QNB>(ch + 3, sl0, sl2, true, R1, R0, bh, colBase, c, h, lane,
                  q, wsNq, wsWb, wsKtb, wsAttnb, wsQnb, wsU, S0, S1, S2, S3, out);
        step<QNB>(ch + 4, sl1, sl0, true, R0, R1, bh, colBase, c, h, lane,
                  q, wsNq, wsWb, wsKtb, wsAttnb, wsQnb, wsU, S0, S1, S2, S3, out);
        step<QNB>(ch + 5, sl2, sl1, true, R1, R0, bh, colBase, c, h, lane,
                  q, wsNq, wsWb, wsKtb, wsAttnb, wsQnb, wsU, S0, S1, S2, S3, out);
    }
    // tail: chunks 126 (slab0, R0) and 127 (slab1, R1), no staging
    step<QNB>(126, sl0, sl2, false, R0, R1, bh, colBase, c, h, lane,
              q, wsNq, wsWb, wsKtb, wsAttnb, wsQnb, wsU, S0, S1, S2, S3, out);
    step<QNB>(127, sl1, sl0, false, R1, R0, bh, colBase, c, h, lane,
              q, wsNq, wsWb, wsKtb, wsAttnb, wsQnb, wsU, S0, S1, S2, S3, out);

    // S_final -> d_out tail
    const size_t soff = (size_t)Bb * Hh * Ll * Dd;
    #pragma unroll
    for (int t = 0; t < 4; ++t) {
        const f32x16& T = (t == 0) ? S0 : (t == 1) ? S1 : (t == 2) ? S2 : S3;
        #pragma unroll
        for (int r = 0; r < 16; ++r) {
            const int row = 32 * t + (r & 3) + 8 * (r >> 2) + 4 * h;
            out[soff + (size_t)bh * Dd * Dd + (size_t)row * Dd + colBase + c] =
                T[r];
        }
    }
}

extern "C" void kernel_launch(void* const* d_in, const int* in_sizes, int n_in,
                              void* d_out, int out_size, void* d_ws,
                              size_t ws_size, hipStream_t stream) {
    const float* q    = (const float*)d_in[0];
    const float* k    = (const float*)d_in[1];
    const float* v    = (const float*)d_in[2];
    const float* beta = (const float*)d_in[3];
    float* out = (float*)d_out;

    const size_t nQK = (size_t)BHn * Ll * Dd;          // 8,388,608
    float* wsU    = (float*)d_ws;                      // fp32, 32 MB
    float* wsNq   = wsU + nQK;                         // fp32, 0.25 MB
    short* wsWb   = (short*)(wsNq + (size_t)BHn * Ll); // bf16, 16 MB
    short* wsKtb  = wsWb + nQK;                        // bf16, 16 MB
    short* wsAttnb = wsKtb + nQK;                      // bf16, 4 MB
    short* wsQnb  = wsAttnb + (size_t)BHn * NC * Cc * Cc; // bf16, 16 MB (opt)
    const size_t need_qnb = (size_t)((char*)(wsQnb + nQK) - (char*)d_ws);

    if (ws_size >= need_qnb) {
        prep_kernel<true><<<dim3(BHn * NC), 256, 0, stream>>>(
            q, k, v, beta, wsU, wsNq, wsWb, wsKtb, wsAttnb, wsQnb);
        scan_kernel<true><<<dim3(BHn, 4), 64, 0, stream>>>(
            q, wsU, wsWb, wsKtb, wsAttnb, wsQnb, wsNq, out);
    } else {
        prep_kernel<false><<<dim3(BHn * NC), 256, 0, stream>>>(
            q, k, v, beta, wsU, wsNq, wsWb, wsKtb, wsAttnb, wsQnb);
        scan_kernel<false><<<dim3(BHn, 4), 64, 0, stream>>>(
            q, wsU, wsWb, wsKtb, wsAttnb, wsQnb, wsNq, out);
    }
}

// Round 5
// 316.676 us; speedup vs baseline: 1.9706x; 1.1043x over previous
//
#include <hip/hip_runtime.h>

// DeltaNet chunkwise delta rule. b=2,h=8,L=4096,d=128,chunk=32.
// R9: scan -> producer/consumer wave specialization (AITER pattern).
//  - R8 lesson: LLVM's waitcnt pass serializes any wave that both issues
//    global_load_lds and ds_reads LDS (conservative vmcnt drain). Fix is
//    structural: wave 1 stages (global->LDS, vmcnt(0) is ITS wait), wave 0
//    computes from LDS only (zero global loads, precise lgkm waits).
//  - 3 x 30.7KB slabs (ALL operands: Wb,Ktb,Qnb,At,U), producer 2 chunks
//    ahead, one s_barrier per chunk.
//  - prep unchanged from R8.

#define Bb 2
#define Hh 8
#define Ll 4096
#define Dd 128
#define DP (Dd + 4)
#define Cc 32
#define CP2 33
#define NC (Ll / Cc)       // 128 chunks
#define BHn (Bb * Hh)      // 16 heads

// slab layout (bytes): 0 Wb[16][32]bf16x8=8192 | 8192 Ktb=8192 |
//   16384 Qnb=8192 | 24576 At[4][32]=2048 | 26624 U[32][32]f32=4096
#define SLAB 30720

typedef float  f32x16 __attribute__((ext_vector_type(16)));
typedef short  bf16x8 __attribute__((ext_vector_type(8)));

#define WAITVM0 asm volatile("s_waitcnt vmcnt(0)" ::: "memory")

__device__ __forceinline__ short f2bf(float x) {
    union { float f; unsigned u; } a; a.f = x;
    const unsigned r = a.u + 0x7FFFu + ((a.u >> 16) & 1u);  // RNE
    return (short)(r >> 16);
}

__device__ __forceinline__ float bf2f(short h) {
    union { unsigned u; float f; } t;
    t.u = ((unsigned)(unsigned short)h) << 16;
    return t.f;
}

__device__ __forceinline__ unsigned cvt_pk_bf16(float lo, float hi) {
    unsigned r;
    asm("v_cvt_pk_bf16_f32 %0, %1, %2" : "=v"(r) : "v"(lo), "v"(hi));
    return r;
}

// C-layout quadrant -> MFMA B-operand fragment for K=16 slice m, via
// v_cvt_pk_bf16_f32 + v_permlane32_swap (VALU only). Proven R5-R8.
__device__ __forceinline__ bf16x8 mk_bop(const f32x16& T, int m) {
    const int o = 8 * m;
    const unsigned a01 = cvt_pk_bf16(T[o + 0], T[o + 1]);
    const unsigned a23 = cvt_pk_bf16(T[o + 2], T[o + 3]);
    const unsigned b01 = cvt_pk_bf16(T[o + 4], T[o + 5]);
    const unsigned b23 = cvt_pk_bf16(T[o + 6], T[o + 7]);
    const auto r0 = __builtin_amdgcn_permlane32_swap(a01, b01, false, false);
    const auto r1 = __builtin_amdgcn_permlane32_swap(a23, b23, false, false);
    union { unsigned u[4]; bf16x8 v; } out;
    out.u[0] = r0[0]; out.u[1] = r1[0]; out.u[2] = r0[1]; out.u[3] = r1[1];
    return out.v;
}

__device__ __forceinline__ void gl_lds16(const void* gsrc, void* ldst) {
    __builtin_amdgcn_global_load_lds(
        (const __attribute__((address_space(1))) unsigned int*)gsrc,
        (__attribute__((address_space(3))) unsigned int*)ldst, 16, 0, 0);
}

// split 8 fp32 into bf16 hi + bf16 residual lo (3-term split-MFMA inputs)
__device__ __forceinline__ void split8(const float4& a, const float4& b,
                                       bf16x8& hi, bf16x8& lo) {
    const float x[8] = {a.x, a.y, a.z, a.w, b.x, b.y, b.z, b.w};
    #pragma unroll
    for (int j = 0; j < 8; ++j) {
        const short hs = f2bf(x[j]);
        hi[j] = hs;
        lo[j] = f2bf(x[j] - bf2f(hs));
    }
}

__device__ __forceinline__ void fma4(float4& acc, float s, const float4& x) {
    acc.x += s * x.x; acc.y += s * x.y; acc.z += s * x.z; acc.w += s * x.w;
}

// ---------------------------------------------------------------------------
// Kernel 1: per-(head,chunk) precompute. 2048 blocks x 256. (unchanged R8)
// ---------------------------------------------------------------------------
template <bool QNB>
__global__ __launch_bounds__(256, 4) void prep_kernel(
    const float* __restrict__ q, const float* __restrict__ k,
    const float* __restrict__ v, const float* __restrict__ beta,
    float* __restrict__ wsU, float* __restrict__ wsNq,
    short* __restrict__ wsWb, short* __restrict__ wsKtb,
    short* __restrict__ wsAttnb, short* __restrict__ wsQnb)
{
    __shared__ float sK[Cc][DP];
    __shared__ float sA[Cc][CP2];
    __shared__ float sInv[Cc][CP2];
    __shared__ float sBeta[Cc], sNk[Cc], sNq[Cc];

    const int tid = threadIdx.x;
    const int blk = blockIdx.x;          // bh*NC + ch
    const int bh = blk / NC;
    const int ch = blk % NC;
    const size_t base = (size_t)(bh * Ll + ch * Cc) * Dd;

    for (int e = tid; e < Cc * Dd / 4; e += 256) {
        const int r = e >> 5, c4 = e & 31;
        ((float4*)&sK[r][0])[c4] = ((const float4*)(k + base))[e];
    }
    if (tid < Cc) sBeta[tid] = beta[bh * Ll + ch * Cc + tid];
    __syncthreads();

    {
        const int row = tid >> 2, part = tid & 3;
        float s = 0.f;
        if (row < Cc) {
            const float4* src = (const float4*)&sK[row][0];
            #pragma unroll
            for (int j = 0; j < 8; ++j) {
                const float4 t = src[part + j * 4];
                s += t.x * t.x + t.y * t.y + t.z * t.z + t.w * t.w;
            }
        } else {
            const float4* src =
                (const float4*)(q + base + (size_t)(row - Cc) * Dd);
            #pragma unroll
            for (int j = 0; j < 8; ++j) {
                const float4 t = src[part + j * 4];
                s += t.x * t.x + t.y * t.y + t.z * t.z + t.w * t.w;
            }
        }
        s += __shfl_xor(s, 1);
        s += __shfl_xor(s, 2);
        if (part == 0) {
            const float r = 1.0f / sqrtf(s);
            if (row < Cc) sNk[row] = r; else sNq[row - Cc] = r;
        }
    }
    __syncthreads();

    if (tid < Cc) wsNq[bh * Ll + ch * Cc + tid] = sNq[tid];

    for (int e = tid; e < Cc * Dd / 4; e += 256) {
        const int r = e >> 5, c4 = e & 31;
        float4 kk = ((float4*)&sK[r][0])[c4];
        const float nk = sNk[r];
        kk.x *= nk; kk.y *= nk; kk.z *= nk; kk.w *= nk;
        ((float4*)&sK[r][0])[c4] = kk;
    }
    __syncthreads();

    const int wid = tid >> 6;
    const int lc = tid & 31;
    const int lh = (tid >> 5) & 1;
    const size_t cbase = (size_t)blk * Cc * Dd;
    const size_t abase = (size_t)blk * Cc * Cc;

    if (wid == 0) {
        f32x16 D, D2;
        #pragma unroll
        for (int r = 0; r < 16; ++r) { D[r] = 0.f; D2[r] = 0.f; }
        #pragma unroll
        for (int ks = 0; ks < 8; ++ks) {
            const float4 a = ((const float4*)&sK[lc][0])[4 * ks + 2 * lh];
            const float4 b = ((const float4*)&sK[lc][0])[4 * ks + 2 * lh + 1];
            bf16x8 hi, lo;
            split8(a, b, hi, lo);
            D  = __builtin_amdgcn_mfma_f32_32x32x16_bf16(hi, hi, D,  0, 0, 0);
            D2 = __builtin_amdgcn_mfma_f32_32x32x16_bf16(hi, lo, D2, 0, 0, 0);
            D2 = __builtin_amdgcn_mfma_f32_32x32x16_bf16(lo, hi, D2, 0, 0, 0);
        }
        #pragma unroll
        for (int r = 0; r < 16; ++r) {
            const int row = (r & 3) + 8 * (r >> 2) + 4 * lh;
            sA[row][lc] = (D[r] + D2[r]) * sBeta[row];
        }
        asm volatile("s_waitcnt lgkmcnt(0)" ::: "memory");
        __builtin_amdgcn_sched_barrier(0);

        float inv[Cc];
        #pragma unroll
        for (int m = 0; m < Cc; ++m) inv[m] = (m == lc) ? 1.f : 0.f;
        #pragma unroll
        for (int i = 1; i < Cc; ++i) {
            float s = 0.f;
            #pragma unroll
            for (int m = 0; m < i; ++m) s += sA[i][m] * inv[m];
            inv[i] = (lc == i) ? 1.f : -s;
        }
        if (lh == 0) {
            #pragma unroll
            for (int m = 0; m < Cc; ++m) sInv[m][lc] = inv[m];
        }
    } else if (wid == 1) {
        const float nq = sNq[lc];
        const float* qrow = q + base + (size_t)lc * Dd;
        f32x16 D, D2;
        #pragma unroll
        for (int r = 0; r < 16; ++r) { D[r] = 0.f; D2[r] = 0.f; }
        #pragma unroll
        for (int ks = 0; ks < 8; ++ks) {
            float4 a = ((const float4*)qrow)[4 * ks + 2 * lh];
            float4 b = ((const float4*)qrow)[4 * ks + 2 * lh + 1];
            a.x *= nq; a.y *= nq; a.z *= nq; a.w *= nq;
            b.x *= nq; b.y *= nq; b.z *= nq; b.w *= nq;
            bf16x8 hiQ, loQ;
            split8(a, b, hiQ, loQ);
            const float4 ka = ((const float4*)&sK[lc][0])[4 * ks + 2 * lh];
            const float4 kb2 = ((const float4*)&sK[lc][0])[4 * ks + 2 * lh + 1];
            bf16x8 hiK, loK;
            split8(ka, kb2, hiK, loK);
            D  = __builtin_amdgcn_mfma_f32_32x32x16_bf16(hiQ, hiK, D,  0, 0, 0);
            D2 = __builtin_amdgcn_mfma_f32_32x32x16_bf16(hiQ, loK, D2, 0, 0, 0);
            D2 = __builtin_amdgcn_mfma_f32_32x32x16_bf16(loQ, hiK, D2, 0, 0, 0);
        }
        #pragma unroll
        for (int r = 0; r < 16; ++r) {
            const int row = (r & 3) + 8 * (r >> 2) + 4 * lh;
            const float val = (lc <= row) ? (D[r] + D2[r]) : 0.f;
            wsAttnb[abase + ((lc >> 3) << 8) + (row << 3) + (lc & 7)] =
                f2bf(val);
        }
    } else {
        const int t = tid - 128;   // 0..127
        #pragma unroll
        for (int it = 0; it < 4; ++it) {
            const int g = t + it * 128;          // 0..511
            const int B = g >> 5, ddl = g & 31;
            const int dd = ((B >> 2) << 5) + ddl;
            const int cc0 = (B & 3) << 3;
            bf16x8 pk;
            #pragma unroll
            for (int j = 0; j < 8; ++j) pk[j] = f2bf(sK[cc0 + j][dd]);
            ((bf16x8*)(wsKtb + cbase))[g] = pk;
        }
        if constexpr (QNB) {
            #pragma unroll
            for (int it = 0; it < 4; ++it) {
                const int g = t + it * 128;      // 0..511
                const int c = g & 31;
                const int dd0 = (g >> 5) << 3;
                const float nq = sNq[c];
                const float4 a =
                    ((const float4*)(q + base + (size_t)c * Dd + dd0))[0];
                const float4 b =
                    ((const float4*)(q + base + (size_t)c * Dd + dd0))[1];
                bf16x8 pk;
                pk[0] = f2bf(a.x * nq); pk[1] = f2bf(a.y * nq);
                pk[2] = f2bf(a.z * nq); pk[3] = f2bf(a.w * nq);
                pk[4] = f2bf(b.x * nq); pk[5] = f2bf(b.y * nq);
                pk[6] = f2bf(b.z * nq); pk[7] = f2bf(b.w * nq);
                ((bf16x8*)(wsQnb + cbase))[g] = pk;
            }
        }
    }
    __syncthreads();

    {
        const int c = tid >> 3, g = tid & 7, dd0 = g * 16;
        float4 u0{}, u1{}, u2{}, u3{}, w0{}, w1{}, w2{}, w3{};
        for (int f = 0; f <= c; ++f) {
            const float ivb = sInv[c][f] * sBeta[f];
            const float4* vr = (const float4*)(v + base + (size_t)f * Dd + dd0);
            const float4* kr = (const float4*)&sK[f][dd0];
            fma4(u0, ivb, vr[0]); fma4(u1, ivb, vr[1]);
            fma4(u2, ivb, vr[2]); fma4(u3, ivb, vr[3]);
            fma4(w0, ivb, kr[0]); fma4(w1, ivb, kr[1]);
            fma4(w2, ivb, kr[2]); fma4(w3, ivb, kr[3]);
        }
        // U in C-frag order: [colblk 4][rh 32][col 32] per chunk
        const int rh = (c & 3) + ((c >> 3) << 2) + (((c >> 2) & 1) << 4);
        const float uu[16] = {u0.x, u0.y, u0.z, u0.w, u1.x, u1.y, u1.z, u1.w,
                              u2.x, u2.y, u2.z, u2.w, u3.x, u3.y, u3.z, u3.w};
        #pragma unroll
        for (int j = 0; j < 16; ++j) {
            const int dd = dd0 + j;
            wsU[cbase + ((dd >> 5) << 10) + (rh << 5) + (dd & 31)] = uu[j];
        }
        bf16x8 p0, p1;
        p0[0] = f2bf(-w0.x); p0[1] = f2bf(-w0.y); p0[2] = f2bf(-w0.z);
        p0[3] = f2bf(-w0.w); p0[4] = f2bf(-w1.x); p0[5] = f2bf(-w1.y);
        p0[6] = f2bf(-w1.z); p0[7] = f2bf(-w1.w);
        p1[0] = f2bf(-w2.x); p1[1] = f2bf(-w2.y); p1[2] = f2bf(-w2.z);
        p1[3] = f2bf(-w2.w); p1[4] = f2bf(-w3.x); p1[5] = f2bf(-w3.y);
        p1[6] = f2bf(-w3.z); p1[7] = f2bf(-w3.w);
        ((bf16x8*)(wsWb + cbase))[(2 * g) * 32 + c] = p0;
        ((bf16x8*)(wsWb + cbase))[(2 * g + 1) * 32 + c] = p1;
    }
}

// ---------------------------------------------------------------------------
// Kernel 2: MFMA scan. 64 blocks x 128 threads.
// Wave 0 = consumer (LDS-only compute). Wave 1 = producer (global->LDS DMA).
// ---------------------------------------------------------------------------
template <bool QNB>
__device__ __forceinline__ void stage_slab(
    char* slab, int bh, int ch, int colBase, int lane,
    const short* __restrict__ wsWb, const short* __restrict__ wsKtb,
    const short* __restrict__ wsQnb, const short* __restrict__ wsAttnb,
    const float* __restrict__ wsU)
{
    const size_t cb = (size_t)(bh * NC + ch) * (Cc * Dd);
    const size_t ab = (size_t)(bh * NC + ch) * (Cc * Cc);
    const char* srcW = (const char*)(wsWb + cb);
    const char* srcK = (const char*)(wsKtb + cb);
    const char* srcA = (const char*)(wsAttnb + ab);
    const int l16 = lane * 16;
    #pragma unroll
    for (int g = 0; g < 8; ++g)
        gl_lds16(srcW + g * 1024 + l16, slab + g * 1024);
    #pragma unroll
    for (int g = 0; g < 8; ++g)
        gl_lds16(srcK + g * 1024 + l16, slab + 8192 + g * 1024);
    if constexpr (QNB) {
        const char* srcQ = (const char*)(wsQnb + cb);
        #pragma unroll
        for (int g = 0; g < 8; ++g)
            gl_lds16(srcQ + g * 1024 + l16, slab + 16384 + g * 1024);
    }
    #pragma unroll
    for (int g = 0; g < 2; ++g)
        gl_lds16(srcA + g * 1024 + l16, slab + 24576 + g * 1024);
    const float* srcU = wsU + cb + (colBase << 5);
    #pragma unroll
    for (int g = 0; g < 4; ++g)
        gl_lds16(srcU + g * 256 + lane * 4, slab + 26624 + g * 1024);
}

template <bool QNB>
__device__ __forceinline__ void compute_chunk(
    const char* slab, int bh, int ch, int colBase, int c, int h,
    const float* __restrict__ q, const float* __restrict__ wsNq,
    f32x16& S0, f32x16& S1, f32x16& S2, f32x16& S3, float* __restrict__ out)
{
    const bf16x8* Wf = (const bf16x8*)slab;
    const bf16x8* Kf = (const bf16x8*)(slab + 8192);
    const bf16x8* Qf = (const bf16x8*)(slab + 16384);
    const bf16x8* Af = (const bf16x8*)(slab + 24576);
    const float*  Uf = (const float*)(slab + 26624);

    bf16x8 qa[8];
    if constexpr (QNB) {
        #pragma unroll
        for (int ks = 0; ks < 8; ++ks) qa[ks] = Qf[(2 * ks + h) * 32 + c];
    } else {
        const size_t qb = (size_t)(bh * Ll + ch * Cc) * Dd;
        const float rq = wsNq[bh * Ll + ch * Cc + c];
        #pragma unroll
        for (int ks = 0; ks < 8; ++ks) {
            const float4 a = ((const float4*)(q + qb))[c * 32 + 4 * ks + 2 * h];
            const float4 b = ((const float4*)(q + qb))[c * 32 + 4 * ks + 2 * h + 1];
            union { unsigned u[4]; bf16x8 v; } t;
            t.u[0] = cvt_pk_bf16(a.x * rq, a.y * rq);
            t.u[1] = cvt_pk_bf16(a.z * rq, a.w * rq);
            t.u[2] = cvt_pk_bf16(b.x * rq, b.y * rq);
            t.u[3] = cvt_pk_bf16(b.z * rq, b.w * rq);
            qa[ks] = t.v;
        }
    }

    f32x16 Ua, Ub, O1, O2;
    #pragma unroll
    for (int r = 0; r < 16; ++r) {
        Ua[r] = Uf[(r + 16 * h) * 32 + c];
        Ub[r] = 0.f; O1[r] = 0.f; O2[r] = 0.f;
    }

    #pragma unroll
    for (int ks = 0; ks < 8; ++ks) {
        const f32x16& T = (ks < 2) ? S0 : (ks < 4) ? S1 : (ks < 6) ? S2 : S3;
        const bf16x8 sB = mk_bop(T, ks & 1);
        const bf16x8 wA = Wf[(2 * ks + h) * 32 + c];
        if (ks < 4)
            Ua = __builtin_amdgcn_mfma_f32_32x32x16_bf16(wA, sB, Ua, 0, 0, 0);
        else
            Ub = __builtin_amdgcn_mfma_f32_32x32x16_bf16(wA, sB, Ub, 0, 0, 0);
        if (ks & 1)
            O2 = __builtin_amdgcn_mfma_f32_32x32x16_bf16(qa[ks], sB, O2, 0, 0, 0);
        else
            O1 = __builtin_amdgcn_mfma_f32_32x32x16_bf16(qa[ks], sB, O1, 0, 0, 0);
    }

    f32x16 Us;
    #pragma unroll
    for (int r = 0; r < 16; ++r) Us[r] = Ua[r] + Ub[r];

    const bf16x8 uB0 = mk_bop(Us, 0);
    const bf16x8 uB1 = mk_bop(Us, 1);

    // S updates first — they gate the next chunk's sB builds.
    S0 = __builtin_amdgcn_mfma_f32_32x32x16_bf16(Kf[(0 + h) * 32 + c],  uB0, S0, 0, 0, 0);
    S0 = __builtin_amdgcn_mfma_f32_32x32x16_bf16(Kf[(2 + h) * 32 + c],  uB1, S0, 0, 0, 0);
    S1 = __builtin_amdgcn_mfma_f32_32x32x16_bf16(Kf[(4 + h) * 32 + c],  uB0, S1, 0, 0, 0);
    S1 = __builtin_amdgcn_mfma_f32_32x32x16_bf16(Kf[(6 + h) * 32 + c],  uB1, S1, 0, 0, 0);
    S2 = __builtin_amdgcn_mfma_f32_32x32x16_bf16(Kf[(8 + h) * 32 + c],  uB0, S2, 0, 0, 0);
    S2 = __builtin_amdgcn_mfma_f32_32x32x16_bf16(Kf[(10 + h) * 32 + c], uB1, S2, 0, 0, 0);
    S3 = __builtin_amdgcn_mfma_f32_32x32x16_bf16(Kf[(12 + h) * 32 + c], uB0, S3, 0, 0, 0);
    S3 = __builtin_amdgcn_mfma_f32_32x32x16_bf16(Kf[(14 + h) * 32 + c], uB1, S3, 0, 0, 0);

    O1 = __builtin_amdgcn_mfma_f32_32x32x16_bf16(Af[(0 + h) * 32 + c], uB0, O1, 0, 0, 0);
    O2 = __builtin_amdgcn_mfma_f32_32x32x16_bf16(Af[(2 + h) * 32 + c], uB1, O2, 0, 0, 0);

    const size_t qb = (size_t)(bh * Ll + ch * Cc) * Dd;
    #pragma unroll
    for (int r = 0; r < 16; ++r) {
        const int row = (r & 3) + 8 * (r >> 2) + 4 * h;
        out[qb + (size_t)row * Dd + colBase + c] = O1[r] + O2[r];
    }
}

template <bool QNB>
__device__ __forceinline__ void pcstep(
    int ch, char* cur, char* nxt, bool dostage, int wid,
    int bh, int colBase, int c, int h, int lane,
    const float* __restrict__ q, const float* __restrict__ wsNq,
    const short* __restrict__ wsWb, const short* __restrict__ wsKtb,
    const short* __restrict__ wsAttnb, const short* __restrict__ wsQnb,
    const float* __restrict__ wsU,
    f32x16& S0, f32x16& S1, f32x16& S2, f32x16& S3, float* __restrict__ out)
{
    if (wid == 0) {
        compute_chunk<QNB>(cur, bh, ch, colBase, c, h, q, wsNq,
                           S0, S1, S2, S3, out);
    } else {
        if (dostage)
            stage_slab<QNB>(nxt, bh, ch + 2, colBase, lane,
                            wsWb, wsKtb, wsQnb, wsAttnb, wsU);
        WAITVM0;
    }
    __builtin_amdgcn_s_barrier();
}

template <bool QNB>
__global__ __launch_bounds__(128, 1) void scan_kernel(
    const float* __restrict__ q, const float* __restrict__ wsU,
    const short* __restrict__ wsWb, const short* __restrict__ wsKtb,
    const short* __restrict__ wsAttnb, const short* __restrict__ wsQnb,
    const float* __restrict__ wsNq, float* __restrict__ out)
{
    __shared__ __attribute__((aligned(16))) char sl0[SLAB];
    __shared__ __attribute__((aligned(16))) char sl1[SLAB];
    __shared__ __attribute__((aligned(16))) char sl2[SLAB];

    const int tid = threadIdx.x;
    const int wid = tid >> 6;       // 0 = consumer, 1 = producer
    const int lane = tid & 63;
    const int h = lane >> 5;
    const int c = lane & 31;
    const int bh = blockIdx.x;
    const int colBase = blockIdx.y * 32;

    f32x16 S0, S1, S2, S3;
    #pragma unroll
    for (int r = 0; r < 16; ++r) { S0[r]=0.f; S1[r]=0.f; S2[r]=0.f; S3[r]=0.f; }

    if (wid == 1) {
        stage_slab<QNB>(sl0, bh, 0, colBase, lane, wsWb, wsKtb, wsQnb,
                        wsAttnb, wsU);
        stage_slab<QNB>(sl1, bh, 1, colBase, lane, wsWb, wsKtb, wsQnb,
                        wsAttnb, wsU);
        WAITVM0;
    }
    __builtin_amdgcn_s_barrier();

    #pragma unroll 1
    for (int it = 0; it < 42; ++it) {
        const int ch = it * 3;
        pcstep<QNB>(ch + 0, sl0, sl2, true, wid, bh, colBase, c, h, lane,
                    q, wsNq, wsWb, wsKtb, wsAttnb, wsQnb, wsU,
                    S0, S1, S2, S3, out);
        pcstep<QNB>(ch + 1, sl1, sl0, true, wid, bh, colBase, c, h, lane,
                    q, wsNq, wsWb, wsKtb, wsAttnb, wsQnb, wsU,
                    S0, S1, S2, S3, out);
        pcstep<QNB>(ch + 2, sl2, sl1, true, wid, bh, colBase, c, h, lane,
                    q, wsNq, wsWb, wsKtb, wsAttnb, wsQnb, wsU,
                    S0, S1, S2, S3, out);
    }
    // tail: chunks 126 (sl0) and 127 (sl1), no staging
    pcstep<QNB>(126, sl0, sl2, false, wid, bh, colBase, c, h, lane,
                q, wsNq, wsWb, wsKtb, wsAttnb, wsQnb, wsU, S0, S1, S2, S3, out);
    pcstep<QNB>(127, sl1, sl0, false, wid, bh, colBase, c, h, lane,
                q, wsNq, wsWb, wsKtb, wsAttnb, wsQnb, wsU, S0, S1, S2, S3, out);

    // S_final -> d_out tail (consumer only)
    if (wid == 0) {
        const size_t soff = (size_t)Bb * Hh * Ll * Dd;
        #pragma unroll
        for (int t = 0; t < 4; ++t) {
            const f32x16& T = (t == 0) ? S0 : (t == 1) ? S1 : (t == 2) ? S2 : S3;
            #pragma unroll
            for (int r = 0; r < 16; ++r) {
                const int row = 32 * t + (r & 3) + 8 * (r >> 2) + 4 * h;
                out[soff + (size_t)bh * Dd * Dd + (size_t)row * Dd + colBase + c]
                    = T[r];
            }
        }
    }
}

extern "C" void kernel_launch(void* const* d_in, const int* in_sizes, int n_in,
                              void* d_out, int out_size, void* d_ws,
                              size_t ws_size, hipStream_t stream) {
    const float* q    = (const float*)d_in[0];
    const float* k    = (const float*)d_in[1];
    const float* v    = (const float*)d_in[2];
    const float* beta = (const float*)d_in[3];
    float* out = (float*)d_out;

    const size_t nQK = (size_t)BHn * Ll * Dd;          // 8,388,608
    float* wsU    = (float*)d_ws;                      // fp32, 32 MB
    float* wsNq   = wsU + nQK;                         // fp32, 0.25 MB
    short* wsWb   = (short*)(wsNq + (size_t)BHn * Ll); // bf16, 16 MB
    short* wsKtb  = wsWb + nQK;                        // bf16, 16 MB
    short* wsAttnb = wsKtb + nQK;                      // bf16, 4 MB
    short* wsQnb  = wsAttnb + (size_t)BHn * NC * Cc * Cc; // bf16, 16 MB (opt)
    const size_t need_qnb = (size_t)((char*)(wsQnb + nQK) - (char*)d_ws);

    if (ws_size >= need_qnb) {
        prep_kernel<true><<<dim3(BHn * NC), 256, 0, stream>>>(
            q, k, v, beta, wsU, wsNq, wsWb, wsKtb, wsAttnb, wsQnb);
        scan_kernel<true><<<dim3(BHn, 4), 128, 0, stream>>>(
            q, wsU, wsWb, wsKtb, wsAttnb, wsQnb, wsNq, out);
    } else {
        prep_kernel<false><<<dim3(BHn * NC), 256, 0, stream>>>(
            q, k, v, beta, wsU, wsNq, wsWb, wsKtb, wsAttnb, wsQnb);
        scan_kernel<false><<<dim3(BHn, 4), 128, 0, stream>>>(
            q, wsU, wsWb, wsKtb, wsAttnb, wsQnb, wsNq, out);
    }
}

// Round 6
// 316.471 us; speedup vs baseline: 1.9719x; 1.0006x over previous
//
#include <hip/hip_runtime.h>

// DeltaNet chunkwise delta rule. b=2,h=8,L=4096,d=128,chunk=32.
// R10: producer wait discipline fixed (T4: counted vmcnt, never 0 in-loop).
//  - R9's producer did stage(ch+2); vmcnt(0) -> paid full round trip per
//    step (2650 cyc/chunk). Now waits vmcnt(30/22): only stage(ch+1) (issued
//    a full step ago) must have landed; newest stage stays in flight.
//  - prep: wave 1's attn hiQ fragments ARE Qnb (same f2bf, same layout) ->
//    store them there; waves 2-3 drop the redundant q re-read/convert loop.
//  - everything else unchanged from R9.

#define Bb 2
#define Hh 8
#define Ll 4096
#define Dd 128
#define DP (Dd + 4)
#define Cc 32
#define CP2 33
#define NC (Ll / Cc)       // 128 chunks
#define BHn (Bb * Hh)      // 16 heads

// slab layout (bytes): 0 Wb[16][32]bf16x8=8192 | 8192 Ktb=8192 |
//   16384 Qnb=8192 | 24576 At[4][32]=2048 | 26624 U[32][32]f32=4096
#define SLAB 30720

typedef float  f32x16 __attribute__((ext_vector_type(16)));
typedef short  bf16x8 __attribute__((ext_vector_type(8)));

#define WAITVM(N) asm volatile("s_waitcnt vmcnt(" #N ")" ::: "memory")

__device__ __forceinline__ short f2bf(float x) {
    union { float f; unsigned u; } a; a.f = x;
    const unsigned r = a.u + 0x7FFFu + ((a.u >> 16) & 1u);  // RNE
    return (short)(r >> 16);
}

__device__ __forceinline__ float bf2f(short h) {
    union { unsigned u; float f; } t;
    t.u = ((unsigned)(unsigned short)h) << 16;
    return t.f;
}

__device__ __forceinline__ unsigned cvt_pk_bf16(float lo, float hi) {
    unsigned r;
    asm("v_cvt_pk_bf16_f32 %0, %1, %2" : "=v"(r) : "v"(lo), "v"(hi));
    return r;
}

// C-layout quadrant -> MFMA B-operand fragment for K=16 slice m, via
// v_cvt_pk_bf16_f32 + v_permlane32_swap (VALU only). Proven R5-R9.
__device__ __forceinline__ bf16x8 mk_bop(const f32x16& T, int m) {
    const int o = 8 * m;
    const unsigned a01 = cvt_pk_bf16(T[o + 0], T[o + 1]);
    const unsigned a23 = cvt_pk_bf16(T[o + 2], T[o + 3]);
    const unsigned b01 = cvt_pk_bf16(T[o + 4], T[o + 5]);
    const unsigned b23 = cvt_pk_bf16(T[o + 6], T[o + 7]);
    const auto r0 = __builtin_amdgcn_permlane32_swap(a01, b01, false, false);
    const auto r1 = __builtin_amdgcn_permlane32_swap(a23, b23, false, false);
    union { unsigned u[4]; bf16x8 v; } out;
    out.u[0] = r0[0]; out.u[1] = r1[0]; out.u[2] = r0[1]; out.u[3] = r1[1];
    return out.v;
}

__device__ __forceinline__ void gl_lds16(const void* gsrc, void* ldst) {
    __builtin_amdgcn_global_load_lds(
        (const __attribute__((address_space(1))) unsigned int*)gsrc,
        (__attribute__((address_space(3))) unsigned int*)ldst, 16, 0, 0);
}

// split 8 fp32 into bf16 hi + bf16 residual lo (3-term split-MFMA inputs)
__device__ __forceinline__ void split8(const float4& a, const float4& b,
                                       bf16x8& hi, bf16x8& lo) {
    const float x[8] = {a.x, a.y, a.z, a.w, b.x, b.y, b.z, b.w};
    #pragma unroll
    for (int j = 0; j < 8; ++j) {
        const short hs = f2bf(x[j]);
        hi[j] = hs;
        lo[j] = f2bf(x[j] - bf2f(hs));
    }
}

__device__ __forceinline__ void fma4(float4& acc, float s, const float4& x) {
    acc.x += s * x.x; acc.y += s * x.y; acc.z += s * x.z; acc.w += s * x.w;
}

// ---------------------------------------------------------------------------
// Kernel 1: per-(head,chunk) precompute. 2048 blocks x 256.
// ---------------------------------------------------------------------------
template <bool QNB>
__global__ __launch_bounds__(256, 4) void prep_kernel(
    const float* __restrict__ q, const float* __restrict__ k,
    const float* __restrict__ v, const float* __restrict__ beta,
    float* __restrict__ wsU, float* __restrict__ wsNq,
    short* __restrict__ wsWb, short* __restrict__ wsKtb,
    short* __restrict__ wsAttnb, short* __restrict__ wsQnb)
{
    __shared__ float sK[Cc][DP];
    __shared__ float sA[Cc][CP2];
    __shared__ float sInv[Cc][CP2];
    __shared__ float sBeta[Cc], sNk[Cc], sNq[Cc];

    const int tid = threadIdx.x;
    const int blk = blockIdx.x;          // bh*NC + ch
    const int bh = blk / NC;
    const int ch = blk % NC;
    const size_t base = (size_t)(bh * Ll + ch * Cc) * Dd;

    for (int e = tid; e < Cc * Dd / 4; e += 256) {
        const int r = e >> 5, c4 = e & 31;
        ((float4*)&sK[r][0])[c4] = ((const float4*)(k + base))[e];
    }
    if (tid < Cc) sBeta[tid] = beta[bh * Ll + ch * Cc + tid];
    __syncthreads();

    {
        const int row = tid >> 2, part = tid & 3;
        float s = 0.f;
        if (row < Cc) {
            const float4* src = (const float4*)&sK[row][0];
            #pragma unroll
            for (int j = 0; j < 8; ++j) {
                const float4 t = src[part + j * 4];
                s += t.x * t.x + t.y * t.y + t.z * t.z + t.w * t.w;
            }
        } else {
            const float4* src =
                (const float4*)(q + base + (size_t)(row - Cc) * Dd);
            #pragma unroll
            for (int j = 0; j < 8; ++j) {
                const float4 t = src[part + j * 4];
                s += t.x * t.x + t.y * t.y + t.z * t.z + t.w * t.w;
            }
        }
        s += __shfl_xor(s, 1);
        s += __shfl_xor(s, 2);
        if (part == 0) {
            const float r = 1.0f / sqrtf(s);
            if (row < Cc) sNk[row] = r; else sNq[row - Cc] = r;
        }
    }
    __syncthreads();

    if (tid < Cc) wsNq[bh * Ll + ch * Cc + tid] = sNq[tid];

    for (int e = tid; e < Cc * Dd / 4; e += 256) {
        const int r = e >> 5, c4 = e & 31;
        float4 kk = ((float4*)&sK[r][0])[c4];
        const float nk = sNk[r];
        kk.x *= nk; kk.y *= nk; kk.z *= nk; kk.w *= nk;
        ((float4*)&sK[r][0])[c4] = kk;
    }
    __syncthreads();

    const int wid = tid >> 6;
    const int lc = tid & 31;
    const int lh = (tid >> 5) & 1;
    const size_t cbase = (size_t)blk * Cc * Dd;
    const size_t abase = (size_t)blk * Cc * Cc;

    if (wid == 0) {
        f32x16 D, D2;
        #pragma unroll
        for (int r = 0; r < 16; ++r) { D[r] = 0.f; D2[r] = 0.f; }
        #pragma unroll
        for (int ks = 0; ks < 8; ++ks) {
            const float4 a = ((const float4*)&sK[lc][0])[4 * ks + 2 * lh];
            const float4 b = ((const float4*)&sK[lc][0])[4 * ks + 2 * lh + 1];
            bf16x8 hi, lo;
            split8(a, b, hi, lo);
            D  = __builtin_amdgcn_mfma_f32_32x32x16_bf16(hi, hi, D,  0, 0, 0);
            D2 = __builtin_amdgcn_mfma_f32_32x32x16_bf16(hi, lo, D2, 0, 0, 0);
            D2 = __builtin_amdgcn_mfma_f32_32x32x16_bf16(lo, hi, D2, 0, 0, 0);
        }
        #pragma unroll
        for (int r = 0; r < 16; ++r) {
            const int row = (r & 3) + 8 * (r >> 2) + 4 * lh;
            sA[row][lc] = (D[r] + D2[r]) * sBeta[row];
        }
        asm volatile("s_waitcnt lgkmcnt(0)" ::: "memory");
        __builtin_amdgcn_sched_barrier(0);

        float inv[Cc];
        #pragma unroll
        for (int m = 0; m < Cc; ++m) inv[m] = (m == lc) ? 1.f : 0.f;
        #pragma unroll
        for (int i = 1; i < Cc; ++i) {
            float s = 0.f;
            #pragma unroll
            for (int m = 0; m < i; ++m) s += sA[i][m] * inv[m];
            inv[i] = (lc == i) ? 1.f : -s;
        }
        if (lh == 0) {
            #pragma unroll
            for (int m = 0; m < Cc; ++m) sInv[m][lc] = inv[m];
        }
    } else if (wid == 1) {
        const float nq = sNq[lc];
        const float* qrow = q + base + (size_t)lc * Dd;
        f32x16 D, D2;
        #pragma unroll
        for (int r = 0; r < 16; ++r) { D[r] = 0.f; D2[r] = 0.f; }
        #pragma unroll
        for (int ks = 0; ks < 8; ++ks) {
            float4 a = ((const float4*)qrow)[4 * ks + 2 * lh];
            float4 b = ((const float4*)qrow)[4 * ks + 2 * lh + 1];
            a.x *= nq; a.y *= nq; a.z *= nq; a.w *= nq;
            b.x *= nq; b.y *= nq; b.z *= nq; b.w *= nq;
            bf16x8 hiQ, loQ;
            split8(a, b, hiQ, loQ);
            if constexpr (QNB) {
                // hiQ == f2bf(q^) == Qnb fragment (2ks+lh, lc): store directly
                ((bf16x8*)(wsQnb + cbase))[(2 * ks + lh) * 32 + lc] = hiQ;
            }
            const float4 ka = ((const float4*)&sK[lc][0])[4 * ks + 2 * lh];
            const float4 kb2 = ((const float4*)&sK[lc][0])[4 * ks + 2 * lh + 1];
            bf16x8 hiK, loK;
            split8(ka, kb2, hiK, loK);
            D  = __builtin_amdgcn_mfma_f32_32x32x16_bf16(hiQ, hiK, D,  0, 0, 0);
            D2 = __builtin_amdgcn_mfma_f32_32x32x16_bf16(hiQ, loK, D2, 0, 0, 0);
            D2 = __builtin_amdgcn_mfma_f32_32x32x16_bf16(loQ, hiK, D2, 0, 0, 0);
        }
        #pragma unroll
        for (int r = 0; r < 16; ++r) {
            const int row = (r & 3) + 8 * (r >> 2) + 4 * lh;
            const float val = (lc <= row) ? (D[r] + D2[r]) : 0.f;
            wsAttnb[abase + ((lc >> 3) << 8) + (row << 3) + (lc & 7)] =
                f2bf(val);
        }
    } else {
        // waves 2-3: Ktb only (Qnb now written by wave 1)
        const int t = tid - 128;   // 0..127
        #pragma unroll
        for (int it = 0; it < 4; ++it) {
            const int g = t + it * 128;          // 0..511
            const int B = g >> 5, ddl = g & 31;
            const int dd = ((B >> 2) << 5) + ddl;
            const int cc0 = (B & 3) << 3;
            bf16x8 pk;
            #pragma unroll
            for (int j = 0; j < 8; ++j) pk[j] = f2bf(sK[cc0 + j][dd]);
            ((bf16x8*)(wsKtb + cbase))[g] = pk;
        }
    }
    __syncthreads();

    {
        const int c = tid >> 3, g = tid & 7, dd0 = g * 16;
        float4 u0{}, u1{}, u2{}, u3{}, w0{}, w1{}, w2{}, w3{};
        for (int f = 0; f <= c; ++f) {
            const float ivb = sInv[c][f] * sBeta[f];
            const float4* vr = (const float4*)(v + base + (size_t)f * Dd + dd0);
            const float4* kr = (const float4*)&sK[f][dd0];
            fma4(u0, ivb, vr[0]); fma4(u1, ivb, vr[1]);
            fma4(u2, ivb, vr[2]); fma4(u3, ivb, vr[3]);
            fma4(w0, ivb, kr[0]); fma4(w1, ivb, kr[1]);
            fma4(w2, ivb, kr[2]); fma4(w3, ivb, kr[3]);
        }
        // U in C-frag order: [colblk 4][rh 32][col 32] per chunk
        const int rh = (c & 3) + ((c >> 3) << 2) + (((c >> 2) & 1) << 4);
        const float uu[16] = {u0.x, u0.y, u0.z, u0.w, u1.x, u1.y, u1.z, u1.w,
                              u2.x, u2.y, u2.z, u2.w, u3.x, u3.y, u3.z, u3.w};
        #pragma unroll
        for (int j = 0; j < 16; ++j) {
            const int dd = dd0 + j;
            wsU[cbase + ((dd >> 5) << 10) + (rh << 5) + (dd & 31)] = uu[j];
        }
        bf16x8 p0, p1;
        p0[0] = f2bf(-w0.x); p0[1] = f2bf(-w0.y); p0[2] = f2bf(-w0.z);
        p0[3] = f2bf(-w0.w); p0[4] = f2bf(-w1.x); p0[5] = f2bf(-w1.y);
        p0[6] = f2bf(-w1.z); p0[7] = f2bf(-w1.w);
        p1[0] = f2bf(-w2.x); p1[1] = f2bf(-w2.y); p1[2] = f2bf(-w2.z);
        p1[3] = f2bf(-w2.w); p1[4] = f2bf(-w3.x); p1[5] = f2bf(-w3.y);
        p1[6] = f2bf(-w3.z); p1[7] = f2bf(-w3.w);
        ((bf16x8*)(wsWb + cbase))[(2 * g) * 32 + c] = p0;
        ((bf16x8*)(wsWb + cbase))[(2 * g + 1) * 32 + c] = p1;
    }
}

// ---------------------------------------------------------------------------
// Kernel 2: MFMA scan. 64 blocks x 128 threads.
// Wave 0 = consumer (LDS-only compute). Wave 1 = producer (global->LDS DMA,
// counted vmcnt — newest stage stays in flight across the barrier).
// ---------------------------------------------------------------------------
template <bool QNB>
__device__ __forceinline__ void stage_slab(
    char* slab, int bh, int ch, int colBase, int lane,
    const short* __restrict__ wsWb, const short* __restrict__ wsKtb,
    const short* __restrict__ wsQnb, const short* __restrict__ wsAttnb,
    const float* __restrict__ wsU)
{
    const size_t cb = (size_t)(bh * NC + ch) * (Cc * Dd);
    const size_t ab = (size_t)(bh * NC + ch) * (Cc * Cc);
    const char* srcW = (const char*)(wsWb + cb);
    const char* srcK = (const char*)(wsKtb + cb);
    const char* srcA = (const char*)(wsAttnb + ab);
    const int l16 = lane * 16;
    #pragma unroll
    for (int g = 0; g < 8; ++g)
        gl_lds16(srcW + g * 1024 + l16, slab + g * 1024);
    #pragma unroll
    for (int g = 0; g < 8; ++g)
        gl_lds16(srcK + g * 1024 + l16, slab + 8192 + g * 1024);
    if constexpr (QNB) {
        const char* srcQ = (const char*)(wsQnb + cb);
        #pragma unroll
        for (int g = 0; g < 8; ++g)
            gl_lds16(srcQ + g * 1024 + l16, slab + 16384 + g * 1024);
    }
    #pragma unroll
    for (int g = 0; g < 2; ++g)
        gl_lds16(srcA + g * 1024 + l16, slab + 24576 + g * 1024);
    const float* srcU = wsU + cb + (colBase << 5);
    #pragma unroll
    for (int g = 0; g < 4; ++g)
        gl_lds16(srcU + g * 256 + lane * 4, slab + 26624 + g * 1024);
}
// loads per stage: QNB ? 30 : 22

template <bool QNB>
__device__ __forceinline__ void compute_chunk(
    const char* slab, int bh, int ch, int colBase, int c, int h,
    const float* __restrict__ q, const float* __restrict__ wsNq,
    f32x16& S0, f32x16& S1, f32x16& S2, f32x16& S3, float* __restrict__ out)
{
    const bf16x8* Wf = (const bf16x8*)slab;
    const bf16x8* Kf = (const bf16x8*)(slab + 8192);
    const bf16x8* Qf = (const bf16x8*)(slab + 16384);
    const bf16x8* Af = (const bf16x8*)(slab + 24576);
    const float*  Uf = (const float*)(slab + 26624);

    bf16x8 qa[8];
    if constexpr (QNB) {
        #pragma unroll
        for (int ks = 0; ks < 8; ++ks) qa[ks] = Qf[(2 * ks + h) * 32 + c];
    } else {
        const size_t qb = (size_t)(bh * Ll + ch * Cc) * Dd;
        const float rq = wsNq[bh * Ll + ch * Cc + c];
        #pragma unroll
        for (int ks = 0; ks < 8; ++ks) {
            const float4 a = ((const float4*)(q + qb))[c * 32 + 4 * ks + 2 * h];
            const float4 b = ((const float4*)(q + qb))[c * 32 + 4 * ks + 2 * h + 1];
            union { unsigned u[4]; bf16x8 v; } t;
            t.u[0] = cvt_pk_bf16(a.x * rq, a.y * rq);
            t.u[1] = cvt_pk_bf16(a.z * rq, a.w * rq);
            t.u[2] = cvt_pk_bf16(b.x * rq, b.y * rq);
            t.u[3] = cvt_pk_bf16(b.z * rq, b.w * rq);
            qa[ks] = t.v;
        }
    }

    f32x16 Ua, Ub, O1, O2;
    #pragma unroll
    for (int r = 0; r < 16; ++r) {
        Ua[r] = Uf[(r + 16 * h) * 32 + c];
        Ub[r] = 0.f; O1[r] = 0.f; O2[r] = 0.f;
    }

    #pragma unroll
    for (int ks = 0; ks < 8; ++ks) {
        const f32x16& T = (ks < 2) ? S0 : (ks < 4) ? S1 : (ks < 6) ? S2 : S3;
        const bf16x8 sB = mk_bop(T, ks & 1);
        const bf16x8 wA = Wf[(2 * ks + h) * 32 + c];
        if (ks < 4)
            Ua = __builtin_amdgcn_mfma_f32_32x32x16_bf16(wA, sB, Ua, 0, 0, 0);
        else
            Ub = __builtin_amdgcn_mfma_f32_32x32x16_bf16(wA, sB, Ub, 0, 0, 0);
        if (ks & 1)
            O2 = __builtin_amdgcn_mfma_f32_32x32x16_bf16(qa[ks], sB, O2, 0, 0, 0);
        else
            O1 = __builtin_amdgcn_mfma_f32_32x32x16_bf16(qa[ks], sB, O1, 0, 0, 0);
    }

    f32x16 Us;
    #pragma unroll
    for (int r = 0; r < 16; ++r) Us[r] = Ua[r] + Ub[r];

    const bf16x8 uB0 = mk_bop(Us, 0);
    const bf16x8 uB1 = mk_bop(Us, 1);

    // S updates first — they gate the next chunk's sB builds.
    S0 = __builtin_amdgcn_mfma_f32_32x32x16_bf16(Kf[(0 + h) * 32 + c],  uB0, S0, 0, 0, 0);
    S0 = __builtin_amdgcn_mfma_f32_32x32x16_bf16(Kf[(2 + h) * 32 + c],  uB1, S0, 0, 0, 0);
    S1 = __builtin_amdgcn_mfma_f32_32x32x16_bf16(Kf[(4 + h) * 32 + c],  uB0, S1, 0, 0, 0);
    S1 = __builtin_amdgcn_mfma_f32_32x32x16_bf16(Kf[(6 + h) * 32 + c],  uB1, S1, 0, 0, 0);
    S2 = __builtin_amdgcn_mfma_f32_32x32x16_bf16(Kf[(8 + h) * 32 + c],  uB0, S2, 0, 0, 0);
    S2 = __builtin_amdgcn_mfma_f32_32x32x16_bf16(Kf[(10 + h) * 32 + c], uB1, S2, 0, 0, 0);
    S3 = __builtin_amdgcn_mfma_f32_32x32x16_bf16(Kf[(12 + h) * 32 + c], uB0, S3, 0, 0, 0);
    S3 = __builtin_amdgcn_mfma_f32_32x32x16_bf16(Kf[(14 + h) * 32 + c], uB1, S3, 0, 0, 0);

    O1 = __builtin_amdgcn_mfma_f32_32x32x16_bf16(Af[(0 + h) * 32 + c], uB0, O1, 0, 0, 0);
    O2 = __builtin_amdgcn_mfma_f32_32x32x16_bf16(Af[(2 + h) * 32 + c], uB1, O2, 0, 0, 0);

    const size_t qb = (size_t)(bh * Ll + ch * Cc) * Dd;
    #pragma unroll
    for (int r = 0; r < 16; ++r) {
        const int row = (r & 3) + 8 * (r >> 2) + 4 * h;
        out[qb + (size_t)row * Dd + colBase + c] = O1[r] + O2[r];
    }
}

template <bool QNB>
__device__ __forceinline__ void pcstep(
    int ch, char* cur, char* nxt, bool dostage, int wid,
    int bh, int colBase, int c, int h, int lane,
    const float* __restrict__ q, const float* __restrict__ wsNq,
    const short* __restrict__ wsWb, const short* __restrict__ wsKtb,
    const short* __restrict__ wsAttnb, const short* __restrict__ wsQnb,
    const float* __restrict__ wsU,
    f32x16& S0, f32x16& S1, f32x16& S2, f32x16& S3, float* __restrict__ out)
{
    if (wid == 0) {
        compute_chunk<QNB>(cur, bh, ch, colBase, c, h, q, wsNq,
                           S0, S1, S2, S3, out);
    } else {
        if (dostage) {
            stage_slab<QNB>(nxt, bh, ch + 2, colBase, lane,
                            wsWb, wsKtb, wsQnb, wsAttnb, wsU);
            // counted wait: only stage(ch+1) (issued last step) must be done;
            // the just-issued stage(ch+2) stays in flight. NEVER vmcnt(0) here.
            if constexpr (QNB) WAITVM(30); else WAITVM(22);
        } else {
            WAITVM(0);   // epilogue: drain the final outstanding stage
        }
    }
    __builtin_amdgcn_s_barrier();
}

template <bool QNB>
__global__ __launch_bounds__(128, 1) void scan_kernel(
    const float* __restrict__ q, const float* __restrict__ wsU,
    const short* __restrict__ wsWb, const short* __restrict__ wsKtb,
    const short* __restrict__ wsAttnb, const short* __restrict__ wsQnb,
    const float* __restrict__ wsNq, float* __restrict__ out)
{
    __shared__ __attribute__((aligned(16))) char sl0[SLAB];
    __shared__ __attribute__((aligned(16))) char sl1[SLAB];
    __shared__ __attribute__((aligned(16))) char sl2[SLAB];

    const int tid = threadIdx.x;
    const int wid = tid >> 6;       // 0 = consumer, 1 = producer
    const int lane = tid & 63;
    const int h = lane >> 5;
    const int c = lane & 31;
    const int bh = blockIdx.x;
    const int colBase = blockIdx.y * 32;

    f32x16 S0, S1, S2, S3;
    #pragma unroll
    for (int r = 0; r < 16; ++r) { S0[r]=0.f; S1[r]=0.f; S2[r]=0.f; S3[r]=0.f; }

    if (wid == 1) {
        stage_slab<QNB>(sl0, bh, 0, colBase, lane, wsWb, wsKtb, wsQnb,
                        wsAttnb, wsU);
        stage_slab<QNB>(sl1, bh, 1, colBase, lane, wsWb, wsKtb, wsQnb,
                        wsAttnb, wsU);
        // need stage(0) complete; stage(1) may remain in flight
        if constexpr (QNB) WAITVM(30); else WAITVM(22);
    }
    __builtin_amdgcn_s_barrier();

    #pragma unroll 1
    for (int it = 0; it < 42; ++it) {
        const int ch = it * 3;
        pcstep<QNB>(ch + 0, sl0, sl2, true, wid, bh, colBase, c, h, lane,
                    q, wsNq, wsWb, wsKtb, wsAttnb, wsQnb, wsU,
                    S0, S1, S2, S3, out);
        pcstep<QNB>(ch + 1, sl1, sl0, true, wid, bh, colBase, c, h, lane,
                    q, wsNq, wsWb, wsKtb, wsAttnb, wsQnb, wsU,
                    S0, S1, S2, S3, out);
        pcstep<QNB>(ch + 2, sl2, sl1, true, wid, bh, colBase, c, h, lane,
                    q, wsNq, wsWb, wsKtb, wsAttnb, wsQnb, wsU,
                    S0, S1, S2, S3, out);
    }
    // tail: chunks 126 (sl0) and 127 (sl1), no staging
    pcstep<QNB>(126, sl0, sl2, false, wid, bh, colBase, c, h, lane,
                q, wsNq, wsWb, wsKtb, wsAttnb, wsQnb, wsU, S0, S1, S2, S3, out);
    pcstep<QNB>(127, sl1, sl0, false, wid, bh, colBase, c, h, lane,
                q, wsNq, wsWb, wsKtb, wsAttnb, wsQnb, wsU, S0, S1, S2, S3, out);

    // S_final -> d_out tail (consumer only)
    if (wid == 0) {
        const size_t soff = (size_t)Bb * Hh * Ll * Dd;
        #pragma unroll
        for (int t = 0; t < 4; ++t) {
            const f32x16& T = (t == 0) ? S0 : (t == 1) ? S1 : (t == 2) ? S2 : S3;
            #pragma unroll
            for (int r = 0; r < 16; ++r) {
                const int row = 32 * t + (r & 3) + 8 * (r >> 2) + 4 * h;
                out[soff + (size_t)bh * Dd * Dd + (size_t)row * Dd + colBase + c]
                    = T[r];
            }
        }
    }
}

extern "C" void kernel_launch(void* const* d_in, const int* in_sizes, int n_in,
                              void* d_out, int out_size, void* d_ws,
                              size_t ws_size, hipStream_t stream) {
    const float* q    = (const float*)d_in[0];
    const float* k    = (const float*)d_in[1];
    const float* v    = (const float*)d_in[2];
    const float* beta = (const float*)d_in[3];
    float* out = (float*)d_out;

    const size_t nQK = (size_t)BHn * Ll * Dd;          // 8,388,608
    float* wsU    = (float*)d_ws;                      // fp32, 32 MB
    float* wsNq   = wsU + nQK;                         // fp32, 0.25 MB
    short* wsWb   = (short*)(wsNq + (size_t)BHn * Ll); // bf16, 16 MB
    short* wsKtb  = wsWb + nQK;                        // bf16, 16 MB
    short* wsAttnb = wsKtb + nQK;                      // bf16, 4 MB
    short* wsQnb  = wsAttnb + (size_t)BHn * NC * Cc * Cc; // bf16, 16 MB (opt)
    const size_t need_qnb = (size_t)((char*)(wsQnb + nQK) - (char*)d_ws);

    if (ws_size >= need_qnb) {
        prep_kernel<true><<<dim3(BHn * NC), 256, 0, stream>>>(
            q, k, v, beta, wsU, wsNq, wsWb, wsKtb, wsAttnb, wsQnb);
        scan_kernel<true><<<dim3(BHn, 4), 128, 0, stream>>>(
            q, wsU, wsWb, wsKtb, wsAttnb, wsQnb, wsNq, out);
    } else {
        prep_kernel<false><<<dim3(BHn * NC), 256, 0, stream>>>(
            q, k, v, beta, wsU, wsNq, wsWb, wsKtb, wsAttnb, wsQnb);
        scan_kernel<false><<<dim3(BHn, 4), 128, 0, stream>>>(
            q, wsU, wsWb, wsKtb, wsAttnb, wsQnb, wsNq, out);
    }
}